// Round 1
// baseline (1650.024 us; speedup 1.0000x reference)
//
#include <hip/hip_runtime.h>

#define NN 100000
#define NE 1600000

// ---------------- degree count ----------------
__global__ void k_degree(const int* __restrict__ dst, int* __restrict__ cnt) {
    int e = blockIdx.x * blockDim.x + threadIdx.x;
    if (e < NE) atomicAdd(&cnt[dst[e]], 1);
}

// ---------------- scatter x (64 feats) ----------------
__global__ void k_scatter64(const float* __restrict__ x, const int* __restrict__ src,
                            const int* __restrict__ dst, float* __restrict__ agg) {
    int idx = blockIdx.x * blockDim.x + threadIdx.x;   // < 102,400,000
    int e = idx >> 6;
    int f = idx & 63;
    if (e < NE) {
        int s = src[e], d = dst[e];
        atomicAdd(&agg[(long long)d * 64 + f], x[(long long)s * 64 + f]);
    }
}

// ---------------- scatter h1 (128 feats) ----------------
__global__ void k_scatter128(const float* __restrict__ h1, const int* __restrict__ src,
                             const int* __restrict__ dst, float* __restrict__ agg) {
    int idx = blockIdx.x * blockDim.x + threadIdx.x;   // < 204,800,000
    int e = idx >> 7;
    int f = idx & 127;
    if (e < NE) {
        int s = src[e], d = dst[e];
        atomicAdd(&agg[(long long)d * 128 + f], h1[(long long)s * 128 + f]);
    }
}

// ---------------- layer 1: h1 = relu(mean1 @ W1l + b1 + x @ W1r), [64]->[128] ----------------
__global__ __launch_bounds__(256) void k_layer1(
    const float* __restrict__ x, const float* __restrict__ agg1,
    const int* __restrict__ cnt,
    const float* __restrict__ W1l, const float* __restrict__ b1,
    const float* __restrict__ W1r, float* __restrict__ h1) {
    __shared__ float sWl[64 * 128];
    __shared__ float sWr[64 * 128];
    __shared__ float sb[128];
    __shared__ float sx[2][64];
    __shared__ float sm[2][64];
    int tl = threadIdx.x;
    for (int i = tl; i < 64 * 128; i += 256) { sWl[i] = W1l[i]; sWr[i] = W1r[i]; }
    if (tl < 128) sb[tl] = b1[tl];
    int col = tl & 127, nsub = tl >> 7;     // 2 nodes x 128 cols
    int grp = tl >> 6, lane = tl & 63;      // 4 staging groups of 64
    int node0 = blockIdx.x * 32;
    for (int it = 0; it < 32; it += 2) {
        __syncthreads();
        int nodeg = node0 + it + (grp >> 1);
        if (nodeg < NN) {
            if (grp & 1) {
                float c = (float)max(cnt[nodeg], 1);
                sm[grp >> 1][lane] = agg1[(long long)nodeg * 64 + lane] / c;
            } else {
                sx[grp >> 1][lane] = x[(long long)nodeg * 64 + lane];
            }
        }
        __syncthreads();
        int node = node0 + it + nsub;
        if (node < NN) {
            float acc = sb[col];
            #pragma unroll 16
            for (int k = 0; k < 64; ++k)
                acc += sm[nsub][k] * sWl[k * 128 + col] + sx[nsub][k] * sWr[k * 128 + col];
            h1[(long long)node * 128 + col] = fmaxf(acc, 0.0f);
        }
    }
}

// ---------------- layer 2: out = relu(mean2 @ W2l + b2 + h1 @ W2r), [128]->[64] ----------------
__global__ __launch_bounds__(256) void k_layer2(
    const float* __restrict__ h1, const float* __restrict__ agg2,
    const int* __restrict__ cnt,
    const float* __restrict__ W2l, const float* __restrict__ b2,
    const float* __restrict__ W2r, float* __restrict__ out) {
    __shared__ float sWl[128 * 64];
    __shared__ float sWr[128 * 64];
    __shared__ float sb[64];
    __shared__ float sH[4][128];
    __shared__ float sM[4][128];
    int tl = threadIdx.x;
    for (int i = tl; i < 128 * 64; i += 256) { sWl[i] = W2l[i]; sWr[i] = W2r[i]; }
    if (tl < 64) sb[tl] = b2[tl];
    int col = tl & 63, nsub = tl >> 6;      // 4 nodes x 64 cols
    int node0 = blockIdx.x * 32;
    for (int it = 0; it < 32; it += 4) {
        __syncthreads();
        for (int i = tl; i < 4 * 128; i += 256) {
            int n = i >> 7, f = i & 127;
            int node = node0 + it + n;
            if (node < NN) {
                sH[n][f] = h1[(long long)node * 128 + f];
                float c = (float)max(cnt[node], 1);
                sM[n][f] = agg2[(long long)node * 128 + f] / c;
            }
        }
        __syncthreads();
        int node = node0 + it + nsub;
        if (node < NN) {
            float acc = sb[col];
            #pragma unroll 16
            for (int k = 0; k < 128; ++k)
                acc += sM[nsub][k] * sWl[k * 64 + col] + sH[nsub][k] * sWr[k * 64 + col];
            out[(long long)node * 64 + col] = fmaxf(acc, 0.0f);
        }
    }
}

extern "C" void kernel_launch(void* const* d_in, const int* in_sizes, int n_in,
                              void* d_out, int out_size, void* d_ws, size_t ws_size,
                              hipStream_t stream) {
    const float* x   = (const float*)d_in[0];
    const int*   ei  = (const int*)d_in[1];
    const int*   src = ei;            // edge_index[0]
    const int*   dst = ei + NE;       // edge_index[1]
    const float* W1l = (const float*)d_in[2];
    const float* b1  = (const float*)d_in[3];
    const float* W1r = (const float*)d_in[4];
    const float* W2l = (const float*)d_in[5];
    const float* b2  = (const float*)d_in[6];
    const float* W2r = (const float*)d_in[7];
    float* out = (float*)d_out;

    // workspace layout (bytes):
    //   [0, 400384)            cnt  (int[100000], padded)
    //   [400384, 26000384)     agg1 (float[100000*64])
    //   [26000384, 77200384)   agg2 (float[100000*128])
    //   [77200384, 128400384)  h1   (float[100000*128])
    char* ws = (char*)d_ws;
    int*   cnt  = (int*)ws;
    float* agg1 = (float*)(ws + 400384);
    float* agg2 = (float*)(ws + 26000384);
    float* h1   = (float*)(ws + 77200384);

    // zero cnt + agg1 + agg2 (contiguous prefix)
    hipMemsetAsync(d_ws, 0, 77200384, stream);

    k_degree<<<(NE + 255) / 256, 256, 0, stream>>>(dst, cnt);
    k_scatter64<<<(NE * 64) / 256, 256, 0, stream>>>(x, src, dst, agg1);
    k_layer1<<<(NN + 31) / 32, 256, 0, stream>>>(x, agg1, cnt, W1l, b1, W1r, h1);
    k_scatter128<<<(NE * 128) / 256, 256, 0, stream>>>(h1, src, dst, agg2);
    k_layer2<<<(NN + 31) / 32, 256, 0, stream>>>(h1, agg2, cnt, W2l, b2, W2r, out);
}

// Round 2
// 1003.404 us; speedup vs baseline: 1.6444x; 1.6444x over previous
//
#include <hip/hip_runtime.h>

#define NN 100000
#define NE 1600000

// ---------------- degree count ----------------
__global__ void k_degree(const int* __restrict__ dst, int* __restrict__ cnt) {
    int e = blockIdx.x * blockDim.x + threadIdx.x;
    if (e < NE) atomicAdd(&cnt[dst[e]], 1);
}

// ---------------- exclusive scan of cnt -> off (single block) ----------------
__global__ __launch_bounds__(512) void k_scan(const int* __restrict__ cnt, int* __restrict__ off) {
    __shared__ int part[512];
    const int CH = 196;  // 512*196 = 100352 >= NN
    int t = threadIdx.x;
    int base = t * CH;
    int s = 0;
    for (int i = 0; i < CH; ++i) {
        int n = base + i;
        if (n < NN) s += cnt[n];
    }
    part[t] = s;
    __syncthreads();
    for (int d = 1; d < 512; d <<= 1) {
        int v = (t >= d) ? part[t - d] : 0;
        __syncthreads();
        part[t] += v;
        __syncthreads();
    }
    int run = (t == 0) ? 0 : part[t - 1];
    for (int i = 0; i < CH; ++i) {
        int n = base + i;
        if (n < NN) { off[n] = run; run += cnt[n]; }
    }
    if (t == 511) off[NN] = run;  // == NE
}

// ---------------- bucket edges by dst: ssrc[off[d]+k] = src ----------------
__global__ void k_bucket(const int* __restrict__ src, const int* __restrict__ dst,
                         const int* __restrict__ off, int* __restrict__ cursor,
                         int* __restrict__ ssrc) {
    int e = blockIdx.x * blockDim.x + threadIdx.x;
    if (e < NE) {
        int d = dst[e];
        int p = atomicAdd(&cursor[d], 1);
        ssrc[off[d] + p] = src[e];
    }
}

// ---------------- gather-mean (F=64): one wave per node ----------------
__global__ __launch_bounds__(256) void k_gather_mean64(
    const float* __restrict__ feat, const int* __restrict__ ssrc,
    const int* __restrict__ off, float* __restrict__ mean) {
    int wid = (blockIdx.x * blockDim.x + threadIdx.x) >> 6;  // node
    int lane = threadIdx.x & 63;
    if (wid >= NN) return;
    int o0 = off[wid], o1 = off[wid + 1];
    float acc = 0.f;
    int j = o0;
    for (; j + 1 < o1; j += 2) {
        int s0 = ssrc[j], s1 = ssrc[j + 1];
        acc += feat[(long long)s0 * 64 + lane];
        acc += feat[(long long)s1 * 64 + lane];
    }
    if (j < o1) acc += feat[(long long)ssrc[j] * 64 + lane];
    int deg = o1 - o0;
    mean[(long long)wid * 64 + lane] = (deg > 0) ? acc / (float)deg : 0.f;
}

// ---------------- gather-mean + add z + relu -> out (final layer tail) ----------------
__global__ __launch_bounds__(256) void k_gather_out(
    const float* __restrict__ y1, const int* __restrict__ ssrc,
    const int* __restrict__ off, const float* __restrict__ z,
    float* __restrict__ out) {
    int wid = (blockIdx.x * blockDim.x + threadIdx.x) >> 6;  // node
    int lane = threadIdx.x & 63;
    if (wid >= NN) return;
    int o0 = off[wid], o1 = off[wid + 1];
    float acc = 0.f;
    int j = o0;
    for (; j + 1 < o1; j += 2) {
        int s0 = ssrc[j], s1 = ssrc[j + 1];
        acc += y1[(long long)s0 * 64 + lane];
        acc += y1[(long long)s1 * 64 + lane];
    }
    if (j < o1) acc += y1[(long long)ssrc[j] * 64 + lane];
    int deg = o1 - o0;
    float m = (deg > 0) ? acc / (float)deg : 0.f;
    out[(long long)wid * 64 + lane] = fmaxf(m + z[(long long)wid * 64 + lane], 0.f);
}

// ---------------- layer 1: h1 = relu(mean1 @ W1l + b1 + x @ W1r), [64]->[128] ----------------
__global__ __launch_bounds__(256) void k_layer1(
    const float* __restrict__ x, const float* __restrict__ mean1,
    const float* __restrict__ W1l, const float* __restrict__ b1,
    const float* __restrict__ W1r, float* __restrict__ h1) {
    __shared__ float sWl[64 * 128];
    __shared__ float sWr[64 * 128];
    __shared__ float sb[128];
    __shared__ float sx[2][64];
    __shared__ float sm[2][64];
    int tl = threadIdx.x;
    for (int i = tl; i < 64 * 128; i += 256) { sWl[i] = W1l[i]; sWr[i] = W1r[i]; }
    if (tl < 128) sb[tl] = b1[tl];
    int col = tl & 127, nsub = tl >> 7;     // 2 nodes x 128 cols
    int grp = tl >> 6, lane = tl & 63;      // 4 staging groups of 64
    int node0 = blockIdx.x * 32;
    for (int it = 0; it < 32; it += 2) {
        __syncthreads();
        int nodeg = node0 + it + (grp >> 1);
        if (nodeg < NN) {
            if (grp & 1) sm[grp >> 1][lane] = mean1[(long long)nodeg * 64 + lane];
            else         sx[grp >> 1][lane] = x[(long long)nodeg * 64 + lane];
        }
        __syncthreads();
        int node = node0 + it + nsub;
        if (node < NN) {
            float acc = sb[col];
            #pragma unroll 16
            for (int k = 0; k < 64; ++k)
                acc += sm[nsub][k] * sWl[k * 128 + col] + sx[nsub][k] * sWr[k * 128 + col];
            h1[(long long)node * 128 + col] = fmaxf(acc, 0.0f);
        }
    }
}

// ---------------- y1 = h1 @ W2l ; z = h1 @ W2r + b2  (both [128]->[64]) ----------------
__global__ __launch_bounds__(256) void k_y1z(
    const float* __restrict__ h1,
    const float* __restrict__ W2l, const float* __restrict__ W2r,
    const float* __restrict__ b2,
    float* __restrict__ y1, float* __restrict__ z) {
    __shared__ float sWl[128 * 64];
    __shared__ float sWr[128 * 64];
    __shared__ float sb[64];
    __shared__ float sH[4][128];
    int tl = threadIdx.x;
    for (int i = tl; i < 128 * 64; i += 256) { sWl[i] = W2l[i]; sWr[i] = W2r[i]; }
    if (tl < 64) sb[tl] = b2[tl];
    int col = tl & 63, nsub = tl >> 6;      // 4 nodes x 64 cols
    int node0 = blockIdx.x * 32;
    for (int it = 0; it < 32; it += 4) {
        __syncthreads();
        for (int i = tl; i < 4 * 128; i += 256) {
            int n = i >> 7, f = i & 127;
            int node = node0 + it + n;
            if (node < NN) sH[n][f] = h1[(long long)node * 128 + f];
        }
        __syncthreads();
        int node = node0 + it + nsub;
        if (node < NN) {
            float accy = 0.f, accz = sb[col];
            #pragma unroll 16
            for (int k = 0; k < 128; ++k) {
                float h = sH[nsub][k];
                accy += h * sWl[k * 64 + col];
                accz += h * sWr[k * 64 + col];
            }
            y1[(long long)node * 64 + col] = accy;
            z[(long long)node * 64 + col]  = accz;
        }
    }
}

extern "C" void kernel_launch(void* const* d_in, const int* in_sizes, int n_in,
                              void* d_out, int out_size, void* d_ws, size_t ws_size,
                              hipStream_t stream) {
    const float* x   = (const float*)d_in[0];
    const int*   ei  = (const int*)d_in[1];
    const int*   src = ei;            // edge_index[0]
    const int*   dst = ei + NE;       // edge_index[1]
    const float* W1l = (const float*)d_in[2];
    const float* b1  = (const float*)d_in[3];
    const float* W1r = (const float*)d_in[4];
    const float* W2l = (const float*)d_in[5];
    const float* b2  = (const float*)d_in[6];
    const float* W2r = (const float*)d_in[7];
    float* out = (float*)d_out;

    // workspace layout (bytes):
    //   [0,        400384)    cnt    (int[NN])
    //   [400384,   800768)    cursor (int[NN])        <- memset covers [0, 800768)
    //   [800768,  1201408)    off    (int[NN+1])
    //   [1201408, 7601408)    ssrc   (int[NE])
    //   [7601408, 33201408)   meanA  (float[NN*64])   <- mean1, later reused as y1
    //   [33201408, 84401408)  h1     (float[NN*128])
    //   [84401408, 110001408) z      (float[NN*64])
    char* ws = (char*)d_ws;
    int*   cnt    = (int*)ws;
    int*   cursor = (int*)(ws + 400384);
    int*   off    = (int*)(ws + 800768);
    int*   ssrc   = (int*)(ws + 1201408);
    float* meanA  = (float*)(ws + 7601408);   // mean1, then y1
    float* h1     = (float*)(ws + 33201408);
    float* z      = (float*)(ws + 84401408);

    hipMemsetAsync(d_ws, 0, 800768, stream);  // cnt + cursor

    k_degree<<<(NE + 255) / 256, 256, 0, stream>>>(dst, cnt);
    k_scan<<<1, 512, 0, stream>>>(cnt, off);
    k_bucket<<<(NE + 255) / 256, 256, 0, stream>>>(src, dst, off, cursor, ssrc);
    // layer 1
    k_gather_mean64<<<(NN * 64 + 255) / 256, 256, 0, stream>>>(x, ssrc, off, meanA);
    k_layer1<<<(NN + 31) / 32, 256, 0, stream>>>(x, meanA, W1l, b1, W1r, h1);
    // layer 2: transform-first (mean(h1)@W2l == mean(h1@W2l))
    float* y1 = meanA;  // mean1 dead after k_layer1
    k_y1z<<<(NN + 31) / 32, 256, 0, stream>>>(h1, W2l, W2r, b2, y1, z);
    k_gather_out<<<(NN * 64 + 255) / 256, 256, 0, stream>>>(y1, ssrc, off, z, out);
}

// Round 5
// 606.777 us; speedup vs baseline: 2.7193x; 1.6537x over previous
//
#include <hip/hip_runtime.h>
#include <hip/hip_bf16.h>

#define NN 100000
#define NE 1600000
#define NROWS 100096   // 782 * 128, padded row count for GEMM tiles

typedef short bf16x8 __attribute__((ext_vector_type(8)));
typedef float f32x4 __attribute__((ext_vector_type(4)));

static __device__ __forceinline__ unsigned short f2bf(float f) {
    __hip_bfloat16 h = __float2bfloat16(f);
    return *reinterpret_cast<unsigned short*>(&h);
}
static __device__ __forceinline__ float bf2f(unsigned short u) {
    union { unsigned int i; float f; } v;
    v.i = ((unsigned int)u) << 16;
    return v.f;
}

#define GLOAD_LDS16(g, l) \
    __builtin_amdgcn_global_load_lds((const __attribute__((address_space(1))) void*)(g), \
                                     (__attribute__((address_space(3))) void*)(l), 16, 0, 0)

// ---------------- degree count ----------------
__global__ void k_degree(const int* __restrict__ dst, int* __restrict__ cnt) {
    int e = blockIdx.x * blockDim.x + threadIdx.x;
    if (e < NE) atomicAdd(&cnt[dst[e]], 1);
}

// ---------------- exclusive scan of cnt -> off (single block) ----------------
__global__ __launch_bounds__(512) void k_scan(const int* __restrict__ cnt, int* __restrict__ off) {
    __shared__ int part[512];
    const int CH = 196;  // 512*196 >= NN
    int t = threadIdx.x;
    int base = t * CH;
    int s = 0;
    for (int i = 0; i < CH; ++i) {
        int n = base + i;
        if (n < NN) s += cnt[n];
    }
    part[t] = s;
    __syncthreads();
    for (int d = 1; d < 512; d <<= 1) {
        int v = (t >= d) ? part[t - d] : 0;
        __syncthreads();
        part[t] += v;
        __syncthreads();
    }
    int run = (t == 0) ? 0 : part[t - 1];
    for (int i = 0; i < CH; ++i) {
        int n = base + i;
        if (n < NN) { off[n] = run; run += cnt[n]; }
    }
    if (t == 511) off[NN] = run;
}

// ---------------- bucket edges by dst ----------------
__global__ void k_bucket(const int* __restrict__ src, const int* __restrict__ dst,
                         const int* __restrict__ off, int* __restrict__ cursor,
                         int* __restrict__ ssrc) {
    int e = blockIdx.x * blockDim.x + threadIdx.x;
    if (e < NE) {
        int d = dst[e];
        int p = atomicAdd(&cursor[d], 1);
        ssrc[off[d] + p] = src[e];
    }
}

// ---------------- weight prep: bf16, N-major (B^T) concatenated ----------------
// Wcat1t[n][k] = k<64 ? W1l[k][n] : W1r[k-64][n]     (n,k in [0,128))
// Wcat2t[n][k] = n<64 ? W2l[k][n] : W2r[k][n-64]
__global__ __launch_bounds__(256) void k_prep_w(
    const float* __restrict__ W1l, const float* __restrict__ W1r,
    const float* __restrict__ W2l, const float* __restrict__ W2r,
    unsigned short* __restrict__ Wcat1t, unsigned short* __restrict__ Wcat2t) {
    for (int i = threadIdx.x; i < 128 * 128; i += 256) {
        int n = i >> 7, k = i & 127;
        float v1 = (k < 64) ? W1l[k * 128 + n] : W1r[(k - 64) * 128 + n];
        Wcat1t[i] = f2bf(v1);
        float v2 = (n < 64) ? W2l[k * 64 + n] : W2r[k * 64 + (n - 64)];
        Wcat2t[i] = f2bf(v2);
    }
}

// ---------------- convert x -> bf16 into Axcat[:,64:128] ----------------
__global__ __launch_bounds__(256) void k_cvt_x(const float* __restrict__ x,
                                               unsigned short* __restrict__ Axcat) {
    int idx = blockIdx.x * blockDim.x + threadIdx.x;  // node*32 + f2
    if (idx >= NN * 32) return;
    int node = idx >> 5, f2 = idx & 31;
    float2 v = *(const float2*)(x + (long long)node * 64 + 2 * f2);
    unsigned int p = (unsigned int)f2bf(v.x) | ((unsigned int)f2bf(v.y) << 16);
    *(unsigned int*)(Axcat + (long long)node * 128 + 64 + 2 * f2) = p;
}

// ---------------- gather-mean of bf16 x-half -> bf16 mean1-half (64 feats) ----------------
// half-wave (32 lanes) per node; lane covers 2 feats via uint load
__global__ __launch_bounds__(256) void k_gather_x(const int* __restrict__ ssrc,
                                                  const int* __restrict__ off,
                                                  unsigned short* __restrict__ Axcat) {
    int wv = (blockIdx.x * blockDim.x + threadIdx.x) >> 6;
    int half = (threadIdx.x >> 5) & 1;
    int lane = threadIdx.x & 31;
    int node = wv * 2 + half;
    if (node >= NN) return;
    int o0 = off[node], o1 = off[node + 1];
    float a0 = 0.f, a1 = 0.f;
    int j = o0;
    for (; j + 1 < o1; j += 2) {
        int s0 = ssrc[j], s1 = ssrc[j + 1];
        unsigned int v0 = *(const unsigned int*)(Axcat + (long long)s0 * 128 + 64 + 2 * lane);
        unsigned int v1 = *(const unsigned int*)(Axcat + (long long)s1 * 128 + 64 + 2 * lane);
        a0 += bf2f((unsigned short)v0) + bf2f((unsigned short)v1);
        a1 += bf2f((unsigned short)(v0 >> 16)) + bf2f((unsigned short)(v1 >> 16));
    }
    if (j < o1) {
        unsigned int v0 = *(const unsigned int*)(Axcat + (long long)ssrc[j] * 128 + 64 + 2 * lane);
        a0 += bf2f((unsigned short)v0);
        a1 += bf2f((unsigned short)(v0 >> 16));
    }
    int deg = o1 - o0;
    float inv = (deg > 0) ? 1.f / (float)deg : 0.f;
    unsigned int p = (unsigned int)f2bf(a0 * inv) | ((unsigned int)f2bf(a1 * inv) << 16);
    *(unsigned int*)(Axcat + (long long)node * 128 + 2 * lane) = p;
}

// ---------------- gather-mean of bf16 y1 + z + relu -> out ----------------
__global__ __launch_bounds__(256) void k_gather_out(const int* __restrict__ ssrc,
                                                    const int* __restrict__ off,
                                                    const unsigned short* __restrict__ y1b,
                                                    const float* __restrict__ zbuf,
                                                    float* __restrict__ out) {
    int wv = (blockIdx.x * blockDim.x + threadIdx.x) >> 6;
    int half = (threadIdx.x >> 5) & 1;
    int lane = threadIdx.x & 31;
    int node = wv * 2 + half;
    if (node >= NN) return;
    int o0 = off[node], o1 = off[node + 1];
    float a0 = 0.f, a1 = 0.f;
    int j = o0;
    for (; j + 1 < o1; j += 2) {
        int s0 = ssrc[j], s1 = ssrc[j + 1];
        unsigned int v0 = *(const unsigned int*)(y1b + (long long)s0 * 64 + 2 * lane);
        unsigned int v1 = *(const unsigned int*)(y1b + (long long)s1 * 64 + 2 * lane);
        a0 += bf2f((unsigned short)v0) + bf2f((unsigned short)v1);
        a1 += bf2f((unsigned short)(v0 >> 16)) + bf2f((unsigned short)(v1 >> 16));
    }
    if (j < o1) {
        unsigned int v0 = *(const unsigned int*)(y1b + (long long)ssrc[j] * 64 + 2 * lane);
        a0 += bf2f((unsigned short)v0);
        a1 += bf2f((unsigned short)(v0 >> 16));
    }
    int deg = o1 - o0;
    float inv = (deg > 0) ? 1.f / (float)deg : 0.f;
    float2 zz = *(const float2*)(zbuf + (long long)node * 64 + 2 * lane);
    float2 o;
    o.x = fmaxf(a0 * inv + zz.x, 0.f);
    o.y = fmaxf(a1 * inv + zz.y, 0.f);
    *(float2*)(out + (long long)node * 64 + 2 * lane) = o;
}

// ---------------- MFMA GEMM: A[NROWS][128]bf16 @ Bt[128][128]bf16 ----------------
// MODE 0: out = relu(A@B + bias[128]) -> bf16 outb[NROWS][128]   (layer1 -> h1)
// MODE 1: cols 0:64 -> bf16 outb[NN][64] (y1); cols 64:128 -> fp32 outf[NN][64] = acc + b2[col-64] (z)
template<int MODE>
__global__ __launch_bounds__(256) void k_gemm(
    const unsigned short* __restrict__ A,
    const unsigned short* __restrict__ Bt,
    const float* __restrict__ bias,
    unsigned short* __restrict__ outb,
    float* __restrict__ outf) {
    __shared__ unsigned short lds[2 * 128 * 128];  // A tile then B, 64 KB
    __shared__ float sBias[128];
    const int tid = threadIdx.x;
    const int wid = tid >> 6;
    const int lane = tid & 63;

    // BUGFIX (round 4): MODE 1 epilogue reads sBias[col] with col in [64,128);
    // previously b2 was stored at [0,64) and z silently lost its bias
    // (absmax 0.0908 == max|b2|).
    if (tid < 128) sBias[tid] = (MODE == 0) ? bias[tid] : ((tid >= 64) ? bias[tid - 64] : 0.f);

    // stage A tile (32KB contiguous) + B (32KB) via global_load_lds, source pre-swizzled
    const char* Ag = (const char*)(A + (long long)blockIdx.x * 128 * 128);
    const char* Bg = (const char*)Bt;
    char* ldsc = (char*)lds;
    #pragma unroll
    for (int j = 0; j < 8; ++j) {
        int g = wid * 512 + j * 64 + lane;        // granule (16B) index in [0,2048)
        int gs = g ^ ((g >> 4) & 7);              // pre-swizzled source granule
        GLOAD_LDS16(Ag + (long long)gs * 16, ldsc + (wid * 8192 + j * 1024));
        GLOAD_LDS16(Bg + (long long)gs * 16, ldsc + 32768 + (wid * 8192 + j * 1024));
    }
    __syncthreads();

    const int rA = lane & 15;
    const int kq = lane >> 4;                     // 0..3
    f32x4 acc[2][8] = {};

    #pragma unroll
    for (int ks = 0; ks < 4; ++ks) {
        const int kbyte = ks * 64 + kq * 16;
        bf16x8 a[2], b[8];
        #pragma unroll
        for (int m = 0; m < 2; ++m) {
            int row = wid * 32 + m * 16 + rA;
            int byte = row * 256 + (kbyte ^ ((row & 7) << 4));
            a[m] = *(const bf16x8*)(ldsc + byte);
        }
        #pragma unroll
        for (int n = 0; n < 8; ++n) {
            int row = n * 16 + rA;
            int byte = 32768 + row * 256 + (kbyte ^ ((row & 7) << 4));
            b[n] = *(const bf16x8*)(ldsc + byte);
        }
        #pragma unroll
        for (int m = 0; m < 2; ++m)
            #pragma unroll
            for (int n = 0; n < 8; ++n)
                acc[m][n] = __builtin_amdgcn_mfma_f32_16x16x32_bf16(a[m], b[n], acc[m][n], 0, 0, 0);
    }

    // epilogue: C/D layout col=lane&15, row=(lane>>4)*4+reg
    #pragma unroll
    for (int m = 0; m < 2; ++m) {
        #pragma unroll
        for (int n = 0; n < 8; ++n) {
            int col = n * 16 + rA;
            long long row0 = (long long)blockIdx.x * 128 + wid * 32 + m * 16 + kq * 4;
            #pragma unroll
            for (int r = 0; r < 4; ++r) {
                long long row = row0 + r;
                if (row < NN) {
                    float v = acc[m][n][r];
                    if (MODE == 0) {
                        v = fmaxf(v + sBias[col], 0.f);
                        outb[row * 128 + col] = f2bf(v);
                    } else {
                        if (col < 64) outb[row * 64 + col] = f2bf(v);
                        else          outf[row * 64 + (col - 64)] = v + sBias[col];
                    }
                }
            }
        }
    }
}

extern "C" void kernel_launch(void* const* d_in, const int* in_sizes, int n_in,
                              void* d_out, int out_size, void* d_ws, size_t ws_size,
                              hipStream_t stream) {
    const float* x   = (const float*)d_in[0];
    const int*   ei  = (const int*)d_in[1];
    const int*   src = ei;
    const int*   dst = ei + NE;
    const float* W1l = (const float*)d_in[2];
    const float* b1  = (const float*)d_in[3];
    const float* W1r = (const float*)d_in[4];
    const float* W2l = (const float*)d_in[5];
    const float* b2  = (const float*)d_in[6];
    const float* W2r = (const float*)d_in[7];
    float* out = (float*)d_out;

    // workspace layout (bytes):
    //   [0,        400384)     cnt    int[NN]
    //   [400384,   800768)     cursor int[NN]           <- memset [0,800768)
    //   [800768,  1201408)     off    int[NN+1]
    //   [1201408, 7601408)     ssrc   int[NE]
    //   [7601408, 33225984)    Axcat  bf16[NROWS][128]  (mean1 | x)
    //   [33225984, 58850560)   h1b    bf16[NROWS][128]
    //   [58850560, 71650560)   y1b    bf16[NN][64]
    //   [71650560, 97250560)   zbuf   f32 [NN][64]
    //   [97250560, 97283328)   Wcat1t bf16[128][128]
    //   [97283328, 97316096)   Wcat2t bf16[128][128]
    char* ws = (char*)d_ws;
    int*   cnt    = (int*)ws;
    int*   cursor = (int*)(ws + 400384);
    int*   off    = (int*)(ws + 800768);
    int*   ssrc   = (int*)(ws + 1201408);
    unsigned short* Axcat = (unsigned short*)(ws + 7601408);
    unsigned short* h1b   = (unsigned short*)(ws + 33225984);
    unsigned short* y1b   = (unsigned short*)(ws + 58850560);
    float*          zbuf  = (float*)(ws + 71650560);
    unsigned short* Wc1   = (unsigned short*)(ws + 97250560);
    unsigned short* Wc2   = (unsigned short*)(ws + 97283328);

    hipMemsetAsync(d_ws, 0, 800768, stream);  // cnt + cursor

    k_degree<<<(NE + 255) / 256, 256, 0, stream>>>(dst, cnt);
    k_scan<<<1, 512, 0, stream>>>(cnt, off);
    k_bucket<<<(NE + 255) / 256, 256, 0, stream>>>(src, dst, off, cursor, ssrc);
    k_prep_w<<<1, 256, 0, stream>>>(W1l, W1r, W2l, W2r, Wc1, Wc2);
    k_cvt_x<<<(NN * 32 + 255) / 256, 256, 0, stream>>>(x, Axcat);
    k_gather_x<<<(NN / 2 * 64 + 255) / 256, 256, 0, stream>>>(ssrc, off, Axcat);
    k_gemm<0><<<NROWS / 128, 256, 0, stream>>>(Axcat, Wc1, b1, h1b, nullptr);
    k_gemm<1><<<NROWS / 128, 256, 0, stream>>>(h1b, Wc2, b2, y1b, zbuf);
    k_gather_out<<<(NN / 2 * 64 + 255) / 256, 256, 0, stream>>>(ssrc, off, y1b, zbuf, out);
}

// Round 6
// 436.963 us; speedup vs baseline: 3.7761x; 1.3886x over previous
//
#include <hip/hip_runtime.h>
#include <hip/hip_bf16.h>

#define NN 100000
#define NE 1600000
#define NROWS 100096   // 782 * 128, padded row count for GEMM tiles
#define NB 391         // ceil(NN/256) scan blocks

typedef short bf16x8 __attribute__((ext_vector_type(8)));
typedef float f32x4 __attribute__((ext_vector_type(4)));

static __device__ __forceinline__ unsigned short f2bf(float f) {
    __hip_bfloat16 h = __float2bfloat16(f);
    return *reinterpret_cast<unsigned short*>(&h);
}
static __device__ __forceinline__ float bf2f(unsigned short u) {
    union { unsigned int i; float f; } v;
    v.i = ((unsigned int)u) << 16;
    return v.f;
}

#define GLOAD_LDS16(g, l) \
    __builtin_amdgcn_global_load_lds((const __attribute__((address_space(1))) void*)(g), \
                                     (__attribute__((address_space(3))) void*)(l), 16, 0, 0)

// ---------------- degree count ----------------
__global__ void k_degree(const int* __restrict__ dst, int* __restrict__ cnt) {
    int e = blockIdx.x * blockDim.x + threadIdx.x;
    if (e < NE) atomicAdd(&cnt[dst[e]], 1);
}

// ---------------- 3-phase multi-block exclusive scan of cnt -> off ----------------
// phase 1: per-block exclusive scan + block sum
__global__ __launch_bounds__(256) void k_scan_blk(const int* __restrict__ cnt,
                                                  int* __restrict__ off,
                                                  int* __restrict__ bsum) {
    __shared__ int sh[256];
    int t = threadIdx.x;
    int n = blockIdx.x * 256 + t;
    int v = (n < NN) ? cnt[n] : 0;
    sh[t] = v;
    __syncthreads();
    #pragma unroll
    for (int d = 1; d < 256; d <<= 1) {
        int add = (t >= d) ? sh[t - d] : 0;
        __syncthreads();
        sh[t] += add;
        __syncthreads();
    }
    if (n < NN) off[n] = sh[t] - v;   // exclusive, block-local
    if (t == 255) bsum[blockIdx.x] = sh[255];
}

// phase 2: scan the NB block sums (single small block)
__global__ __launch_bounds__(512) void k_scan_top(const int* __restrict__ bsum,
                                                  int* __restrict__ boff) {
    __shared__ int sh[512];
    int t = threadIdx.x;
    int v = (t < NB) ? bsum[t] : 0;
    sh[t] = v;
    __syncthreads();
    #pragma unroll
    for (int d = 1; d < 512; d <<= 1) {
        int add = (t >= d) ? sh[t - d] : 0;
        __syncthreads();
        sh[t] += add;
        __syncthreads();
    }
    if (t < NB) boff[t] = sh[t] - v;  // exclusive
}

// phase 3: add block offsets in place; set off[NN]
__global__ __launch_bounds__(256) void k_scan_add(int* __restrict__ off,
                                                  const int* __restrict__ boff) {
    int n = blockIdx.x * 256 + threadIdx.x;
    if (n < NN) off[n] += boff[blockIdx.x];
    if (n == 0) off[NN] = NE;
}

// ---------------- bucket edges by dst ----------------
__global__ void k_bucket(const int* __restrict__ src, const int* __restrict__ dst,
                         const int* __restrict__ off, int* __restrict__ cursor,
                         int* __restrict__ ssrc) {
    int e = blockIdx.x * blockDim.x + threadIdx.x;
    if (e < NE) {
        int d = dst[e];
        int p = atomicAdd(&cursor[d], 1);
        ssrc[off[d] + p] = src[e];
    }
}

// ---------------- weight prep: bf16, N-major (B^T) concatenated ----------------
// Wcat1t[n][k] = k<64 ? W1l[k][n] : W1r[k-64][n]     (n,k in [0,128))
// Wcat2t[n][k] = n<64 ? W2l[k][n] : W2r[k][n-64]
__global__ __launch_bounds__(256) void k_prep_w(
    const float* __restrict__ W1l, const float* __restrict__ W1r,
    const float* __restrict__ W2l, const float* __restrict__ W2r,
    unsigned short* __restrict__ Wcat1t, unsigned short* __restrict__ Wcat2t) {
    for (int i = threadIdx.x; i < 128 * 128; i += 256) {
        int n = i >> 7, k = i & 127;
        float v1 = (k < 64) ? W1l[k * 128 + n] : W1r[(k - 64) * 128 + n];
        Wcat1t[i] = f2bf(v1);
        float v2 = (n < 64) ? W2l[k * 64 + n] : W2r[k * 64 + (n - 64)];
        Wcat2t[i] = f2bf(v2);
    }
}

// ---------------- convert x -> bf16 into Axcat[:,64:128] ----------------
__global__ __launch_bounds__(256) void k_cvt_x(const float* __restrict__ x,
                                               unsigned short* __restrict__ Axcat) {
    int idx = blockIdx.x * blockDim.x + threadIdx.x;  // node*32 + f2
    if (idx >= NN * 32) return;
    int node = idx >> 5, f2 = idx & 31;
    float2 v = *(const float2*)(x + (long long)node * 64 + 2 * f2);
    unsigned int p = (unsigned int)f2bf(v.x) | ((unsigned int)f2bf(v.y) << 16);
    *(unsigned int*)(Axcat + (long long)node * 128 + 64 + 2 * f2) = p;
}

// ---------------- gather-mean of bf16 x-half -> bf16 mean1-half (64 feats) ----------------
// half-wave (32 lanes) per node; lane covers 2 feats via uint load
__global__ __launch_bounds__(256) void k_gather_x(const int* __restrict__ ssrc,
                                                  const int* __restrict__ off,
                                                  unsigned short* __restrict__ Axcat) {
    int wv = (blockIdx.x * blockDim.x + threadIdx.x) >> 6;
    int half = (threadIdx.x >> 5) & 1;
    int lane = threadIdx.x & 31;
    int node = wv * 2 + half;
    if (node >= NN) return;
    int o0 = off[node], o1 = off[node + 1];
    float a0 = 0.f, a1 = 0.f;
    int j = o0;
    for (; j + 1 < o1; j += 2) {
        int s0 = ssrc[j], s1 = ssrc[j + 1];
        unsigned int v0 = *(const unsigned int*)(Axcat + (long long)s0 * 128 + 64 + 2 * lane);
        unsigned int v1 = *(const unsigned int*)(Axcat + (long long)s1 * 128 + 64 + 2 * lane);
        a0 += bf2f((unsigned short)v0) + bf2f((unsigned short)v1);
        a1 += bf2f((unsigned short)(v0 >> 16)) + bf2f((unsigned short)(v1 >> 16));
    }
    if (j < o1) {
        unsigned int v0 = *(const unsigned int*)(Axcat + (long long)ssrc[j] * 128 + 64 + 2 * lane);
        a0 += bf2f((unsigned short)v0);
        a1 += bf2f((unsigned short)(v0 >> 16));
    }
    int deg = o1 - o0;
    float inv = (deg > 0) ? 1.f / (float)deg : 0.f;
    unsigned int p = (unsigned int)f2bf(a0 * inv) | ((unsigned int)f2bf(a1 * inv) << 16);
    *(unsigned int*)(Axcat + (long long)node * 128 + 2 * lane) = p;
}

// ---------------- gather-mean of bf16 y1 + z + relu -> out ----------------
__global__ __launch_bounds__(256) void k_gather_out(const int* __restrict__ ssrc,
                                                    const int* __restrict__ off,
                                                    const unsigned short* __restrict__ y1b,
                                                    const float* __restrict__ zbuf,
                                                    float* __restrict__ out) {
    int wv = (blockIdx.x * blockDim.x + threadIdx.x) >> 6;
    int half = (threadIdx.x >> 5) & 1;
    int lane = threadIdx.x & 31;
    int node = wv * 2 + half;
    if (node >= NN) return;
    int o0 = off[node], o1 = off[node + 1];
    float a0 = 0.f, a1 = 0.f;
    int j = o0;
    for (; j + 1 < o1; j += 2) {
        int s0 = ssrc[j], s1 = ssrc[j + 1];
        unsigned int v0 = *(const unsigned int*)(y1b + (long long)s0 * 64 + 2 * lane);
        unsigned int v1 = *(const unsigned int*)(y1b + (long long)s1 * 64 + 2 * lane);
        a0 += bf2f((unsigned short)v0) + bf2f((unsigned short)v1);
        a1 += bf2f((unsigned short)(v0 >> 16)) + bf2f((unsigned short)(v1 >> 16));
    }
    if (j < o1) {
        unsigned int v0 = *(const unsigned int*)(y1b + (long long)ssrc[j] * 64 + 2 * lane);
        a0 += bf2f((unsigned short)v0);
        a1 += bf2f((unsigned short)(v0 >> 16));
    }
    int deg = o1 - o0;
    float inv = (deg > 0) ? 1.f / (float)deg : 0.f;
    float2 zz = *(const float2*)(zbuf + (long long)node * 64 + 2 * lane);
    float2 o;
    o.x = fmaxf(a0 * inv + zz.x, 0.f);
    o.y = fmaxf(a1 * inv + zz.y, 0.f);
    *(float2*)(out + (long long)node * 64 + 2 * lane) = o;
}

// ---------------- MFMA GEMM: A[NROWS][128]bf16 @ Bt[128][128]bf16 ----------------
// MODE 0: out = relu(A@B + bias[128]) -> bf16 outb[NROWS][128]   (layer1 -> h1)
// MODE 1: cols 0:64 -> bf16 outb[NN][64] (y1); cols 64:128 -> fp32 outf[NN][64] = acc + b2[col-64] (z)
template<int MODE>
__global__ __launch_bounds__(256) void k_gemm(
    const unsigned short* __restrict__ A,
    const unsigned short* __restrict__ Bt,
    const float* __restrict__ bias,
    unsigned short* __restrict__ outb,
    float* __restrict__ outf) {
    __shared__ unsigned short lds[2 * 128 * 128];  // A tile then B, 64 KB
    __shared__ float sBias[128];
    const int tid = threadIdx.x;
    const int wid = tid >> 6;
    const int lane = tid & 63;

    // MODE 1 epilogue reads sBias[col] with col in [64,128) -> store b2 there.
    if (tid < 128) sBias[tid] = (MODE == 0) ? bias[tid] : ((tid >= 64) ? bias[tid - 64] : 0.f);

    // stage A tile (32KB contiguous) + B (32KB) via global_load_lds, source pre-swizzled
    const char* Ag = (const char*)(A + (long long)blockIdx.x * 128 * 128);
    const char* Bg = (const char*)Bt;
    char* ldsc = (char*)lds;
    #pragma unroll
    for (int j = 0; j < 8; ++j) {
        int g = wid * 512 + j * 64 + lane;        // granule (16B) index in [0,2048)
        int gs = g ^ ((g >> 4) & 7);              // pre-swizzled source granule
        GLOAD_LDS16(Ag + (long long)gs * 16, ldsc + (wid * 8192 + j * 1024));
        GLOAD_LDS16(Bg + (long long)gs * 16, ldsc + 32768 + (wid * 8192 + j * 1024));
    }
    __syncthreads();

    const int rA = lane & 15;
    const int kq = lane >> 4;                     // 0..3
    f32x4 acc[2][8] = {};

    #pragma unroll
    for (int ks = 0; ks < 4; ++ks) {
        const int kbyte = ks * 64 + kq * 16;
        bf16x8 a[2], b[8];
        #pragma unroll
        for (int m = 0; m < 2; ++m) {
            int row = wid * 32 + m * 16 + rA;
            int byte = row * 256 + (kbyte ^ ((row & 7) << 4));
            a[m] = *(const bf16x8*)(ldsc + byte);
        }
        #pragma unroll
        for (int n = 0; n < 8; ++n) {
            int row = n * 16 + rA;
            int byte = 32768 + row * 256 + (kbyte ^ ((row & 7) << 4));
            b[n] = *(const bf16x8*)(ldsc + byte);
        }
        #pragma unroll
        for (int m = 0; m < 2; ++m)
            #pragma unroll
            for (int n = 0; n < 8; ++n)
                acc[m][n] = __builtin_amdgcn_mfma_f32_16x16x32_bf16(a[m], b[n], acc[m][n], 0, 0, 0);
    }

    // epilogue: C/D layout col=lane&15, row=(lane>>4)*4+reg
    #pragma unroll
    for (int m = 0; m < 2; ++m) {
        #pragma unroll
        for (int n = 0; n < 8; ++n) {
            int col = n * 16 + rA;
            long long row0 = (long long)blockIdx.x * 128 + wid * 32 + m * 16 + kq * 4;
            #pragma unroll
            for (int r = 0; r < 4; ++r) {
                long long row = row0 + r;
                if (row < NN) {
                    float v = acc[m][n][r];
                    if (MODE == 0) {
                        v = fmaxf(v + sBias[col], 0.f);
                        outb[row * 128 + col] = f2bf(v);
                    } else {
                        if (col < 64) outb[row * 64 + col] = f2bf(v);
                        else          outf[row * 64 + (col - 64)] = v + sBias[col];
                    }
                }
            }
        }
    }
}

extern "C" void kernel_launch(void* const* d_in, const int* in_sizes, int n_in,
                              void* d_out, int out_size, void* d_ws, size_t ws_size,
                              hipStream_t stream) {
    const float* x   = (const float*)d_in[0];
    const int*   ei  = (const int*)d_in[1];
    const int*   src = ei;
    const int*   dst = ei + NE;
    const float* W1l = (const float*)d_in[2];
    const float* b1  = (const float*)d_in[3];
    const float* W1r = (const float*)d_in[4];
    const float* W2l = (const float*)d_in[5];
    const float* b2  = (const float*)d_in[6];
    const float* W2r = (const float*)d_in[7];
    float* out = (float*)d_out;

    // workspace layout (bytes):
    //   [0,        400384)     cnt    int[NN]
    //   [400384,   800768)     cursor int[NN]           <- memset [0,800768)
    //   [800768,  1201408)     off    int[NN+1]
    //   [1201408, 7601408)     ssrc   int[NE]
    //   [7601408, 33225984)    Axcat  bf16[NROWS][128]  (mean1 | x)
    //   [33225984, 58850560)   h1b    bf16[NROWS][128]
    //   [58850560, 71650560)   y1b    bf16[NN][64]
    //   [71650560, 97250560)   zbuf   f32 [NN][64]
    //   [97250560, 97283328)   Wcat1t bf16[128][128]
    //   [97283328, 97316096)   Wcat2t bf16[128][128]
    //   [97316096, 97317696)   bsum   int[400]
    //   [97317696, 97319296)   boff   int[400]
    char* ws = (char*)d_ws;
    int*   cnt    = (int*)ws;
    int*   cursor = (int*)(ws + 400384);
    int*   off    = (int*)(ws + 800768);
    int*   ssrc   = (int*)(ws + 1201408);
    unsigned short* Axcat = (unsigned short*)(ws + 7601408);
    unsigned short* h1b   = (unsigned short*)(ws + 33225984);
    unsigned short* y1b   = (unsigned short*)(ws + 58850560);
    float*          zbuf  = (float*)(ws + 71650560);
    unsigned short* Wc1   = (unsigned short*)(ws + 97250560);
    unsigned short* Wc2   = (unsigned short*)(ws + 97283328);
    int*   bsum   = (int*)(ws + 97316096);
    int*   boff   = (int*)(ws + 97317696);

    hipMemsetAsync(d_ws, 0, 800768, stream);  // cnt + cursor

    k_degree<<<(NE + 255) / 256, 256, 0, stream>>>(dst, cnt);
    k_scan_blk<<<NB, 256, 0, stream>>>(cnt, off, bsum);
    k_scan_top<<<1, 512, 0, stream>>>(bsum, boff);
    k_scan_add<<<NB, 256, 0, stream>>>(off, boff);
    k_bucket<<<(NE + 255) / 256, 256, 0, stream>>>(src, dst, off, cursor, ssrc);
    k_prep_w<<<1, 256, 0, stream>>>(W1l, W1r, W2l, W2r, Wc1, Wc2);
    k_cvt_x<<<(NN * 32 + 255) / 256, 256, 0, stream>>>(x, Axcat);
    k_gather_x<<<(NN / 2 * 64 + 255) / 256, 256, 0, stream>>>(ssrc, off, Axcat);
    k_gemm<0><<<NROWS / 128, 256, 0, stream>>>(Axcat, Wc1, b1, h1b, nullptr);
    k_gemm<1><<<NROWS / 128, 256, 0, stream>>>(h1b, Wc2, b2, y1b, zbuf);
    k_gather_out<<<(NN / 2 * 64 + 255) / 256, 256, 0, stream>>>(ssrc, off, y1b, zbuf, out);
}

// Round 7
// 396.995 us; speedup vs baseline: 4.1563x; 1.1007x over previous
//
#include <hip/hip_runtime.h>
#include <hip/hip_bf16.h>

#define NN 100000
#define NE 1600000
#define NROWS 100096   // 782 * 128, padded row count for GEMM tiles
#define NB 391         // ceil(NN/256) scan blocks
#define NBIN 782       // ceil(NN/128) bins of 128 nodes
#define CAP 4096       // max edges per bin (mean 2046, sigma ~45)

typedef short bf16x8 __attribute__((ext_vector_type(8)));
typedef float f32x4 __attribute__((ext_vector_type(4)));

static __device__ __forceinline__ unsigned short f2bf(float f) {
    __hip_bfloat16 h = __float2bfloat16(f);
    return *reinterpret_cast<unsigned short*>(&h);
}
static __device__ __forceinline__ float bf2f(unsigned short u) {
    union { unsigned int i; float f; } v;
    v.i = ((unsigned int)u) << 16;
    return v.f;
}

#define GLOAD_LDS16(g, l) \
    __builtin_amdgcn_global_load_lds((const __attribute__((address_space(1))) void*)(g), \
                                     (__attribute__((address_space(3))) void*)(l), 16, 0, 0)

// ---------------- pass A: bin edges by dst>>7 into fixed-capacity segments ----------------
__global__ void k_binA(const int* __restrict__ src, const int* __restrict__ dst,
                       int* __restrict__ bin_cnt /* stride 16 ints */,
                       int2* __restrict__ pairs) {
    int e = blockIdx.x * blockDim.x + threadIdx.x;
    if (e < NE) {
        int s = src[e], d = dst[e];
        int b = d >> 7;
        int p = atomicAdd(&bin_cnt[b * 16], 1);
        if (p < CAP) pairs[(long long)b * CAP + p] = make_int2(s, d);
    }
}

// ---------------- pass B1: per-bin degree count -> coalesced cnt write ----------------
__global__ __launch_bounds__(256) void k_binCount(const int2* __restrict__ pairs,
                                                  const int* __restrict__ bin_cnt,
                                                  int* __restrict__ cnt) {
    __shared__ int lcnt[128];
    int b = blockIdx.x, t = threadIdx.x;
    if (t < 128) lcnt[t] = 0;
    __syncthreads();
    int n = min(bin_cnt[b * 16], CAP);
    for (int i = t; i < n; i += 256)
        atomicAdd(&lcnt[pairs[(long long)b * CAP + i].y & 127], 1);
    __syncthreads();
    int node = b * 128 + t;
    if (t < 128 && node < NN) cnt[node] = lcnt[t];
}

// ---------------- 3-phase multi-block exclusive scan of cnt -> off ----------------
__global__ __launch_bounds__(256) void k_scan_blk(const int* __restrict__ cnt,
                                                  int* __restrict__ off,
                                                  int* __restrict__ bsum) {
    __shared__ int sh[256];
    int t = threadIdx.x;
    int n = blockIdx.x * 256 + t;
    int v = (n < NN) ? cnt[n] : 0;
    sh[t] = v;
    __syncthreads();
    #pragma unroll
    for (int d = 1; d < 256; d <<= 1) {
        int add = (t >= d) ? sh[t - d] : 0;
        __syncthreads();
        sh[t] += add;
        __syncthreads();
    }
    if (n < NN) off[n] = sh[t] - v;
    if (t == 255) bsum[blockIdx.x] = sh[255];
}

__global__ __launch_bounds__(512) void k_scan_top(const int* __restrict__ bsum,
                                                  int* __restrict__ boff) {
    __shared__ int sh[512];
    int t = threadIdx.x;
    int v = (t < NB) ? bsum[t] : 0;
    sh[t] = v;
    __syncthreads();
    #pragma unroll
    for (int d = 1; d < 512; d <<= 1) {
        int add = (t >= d) ? sh[t - d] : 0;
        __syncthreads();
        sh[t] += add;
        __syncthreads();
    }
    if (t < NB) boff[t] = sh[t] - v;
}

__global__ __launch_bounds__(256) void k_scan_add(int* __restrict__ off,
                                                  const int* __restrict__ boff) {
    int n = blockIdx.x * 256 + threadIdx.x;
    if (n < NN) off[n] += boff[blockIdx.x];
    if (n == 0) off[NN] = NE;
}

// ---------------- pass B2: per-bin LDS scatter -> sequential ssrc dump ----------------
__global__ __launch_bounds__(256) void k_binPlace(const int2* __restrict__ pairs,
                                                  const int* __restrict__ bin_cnt,
                                                  const int* __restrict__ off,
                                                  int* __restrict__ ssrc) {
    __shared__ int sbuf[CAP];
    __shared__ int soff[129];
    __shared__ int lcur[128];
    int b = blockIdx.x, t = threadIdx.x;
    if (t < 128) lcur[t] = 0;
    if (t < 129) soff[t] = off[min(b * 128 + t, NN)];
    __syncthreads();
    int seg0 = soff[0];
    int n = min(bin_cnt[b * 16], CAP);
    for (int i = t; i < n; i += 256) {
        int2 pr = pairs[(long long)b * CAP + i];
        int dl = pr.y & 127;
        int lp = atomicAdd(&lcur[dl], 1);
        sbuf[soff[dl] - seg0 + lp] = pr.x;
    }
    __syncthreads();
    int len = soff[128] - seg0;
    for (int i = t; i < len; i += 256)
        ssrc[seg0 + i] = sbuf[i];
}

// ---------------- weight prep: bf16, N-major (B^T) concatenated ----------------
__global__ __launch_bounds__(256) void k_prep_w(
    const float* __restrict__ W1l, const float* __restrict__ W1r,
    const float* __restrict__ W2l, const float* __restrict__ W2r,
    unsigned short* __restrict__ Wcat1t, unsigned short* __restrict__ Wcat2t) {
    for (int i = threadIdx.x; i < 128 * 128; i += 256) {
        int n = i >> 7, k = i & 127;
        float v1 = (k < 64) ? W1l[k * 128 + n] : W1r[(k - 64) * 128 + n];
        Wcat1t[i] = f2bf(v1);
        float v2 = (n < 64) ? W2l[k * 64 + n] : W2r[k * 64 + (n - 64)];
        Wcat2t[i] = f2bf(v2);
    }
}

// ---------------- convert x -> bf16 into Axcat[:,64:128] ----------------
__global__ __launch_bounds__(256) void k_cvt_x(const float* __restrict__ x,
                                               unsigned short* __restrict__ Axcat) {
    int idx = blockIdx.x * blockDim.x + threadIdx.x;  // node*32 + f2
    if (idx >= NN * 32) return;
    int node = idx >> 5, f2 = idx & 31;
    float2 v = *(const float2*)(x + (long long)node * 64 + 2 * f2);
    unsigned int p = (unsigned int)f2bf(v.x) | ((unsigned int)f2bf(v.y) << 16);
    *(unsigned int*)(Axcat + (long long)node * 128 + 64 + 2 * f2) = p;
}

// ---------------- gather-mean of bf16 x-half -> bf16 mean1-half (64 feats) ----------------
__global__ __launch_bounds__(256) void k_gather_x(const int* __restrict__ ssrc,
                                                  const int* __restrict__ off,
                                                  unsigned short* __restrict__ Axcat) {
    int wv = (blockIdx.x * blockDim.x + threadIdx.x) >> 6;
    int half = (threadIdx.x >> 5) & 1;
    int lane = threadIdx.x & 31;
    int node = wv * 2 + half;
    if (node >= NN) return;
    int o0 = off[node], o1 = off[node + 1];
    float a0 = 0.f, a1 = 0.f;
    int j = o0;
    for (; j + 1 < o1; j += 2) {
        int s0 = ssrc[j], s1 = ssrc[j + 1];
        unsigned int v0 = *(const unsigned int*)(Axcat + (long long)s0 * 128 + 64 + 2 * lane);
        unsigned int v1 = *(const unsigned int*)(Axcat + (long long)s1 * 128 + 64 + 2 * lane);
        a0 += bf2f((unsigned short)v0) + bf2f((unsigned short)v1);
        a1 += bf2f((unsigned short)(v0 >> 16)) + bf2f((unsigned short)(v1 >> 16));
    }
    if (j < o1) {
        unsigned int v0 = *(const unsigned int*)(Axcat + (long long)ssrc[j] * 128 + 64 + 2 * lane);
        a0 += bf2f((unsigned short)v0);
        a1 += bf2f((unsigned short)(v0 >> 16));
    }
    int deg = o1 - o0;
    float inv = (deg > 0) ? 1.f / (float)deg : 0.f;
    unsigned int p = (unsigned int)f2bf(a0 * inv) | ((unsigned int)f2bf(a1 * inv) << 16);
    *(unsigned int*)(Axcat + (long long)node * 128 + 2 * lane) = p;
}

// ---------------- gather-mean of bf16 y1 + z + relu -> out ----------------
__global__ __launch_bounds__(256) void k_gather_out(const int* __restrict__ ssrc,
                                                    const int* __restrict__ off,
                                                    const unsigned short* __restrict__ y1b,
                                                    const float* __restrict__ zbuf,
                                                    float* __restrict__ out) {
    int wv = (blockIdx.x * blockDim.x + threadIdx.x) >> 6;
    int half = (threadIdx.x >> 5) & 1;
    int lane = threadIdx.x & 31;
    int node = wv * 2 + half;
    if (node >= NN) return;
    int o0 = off[node], o1 = off[node + 1];
    float a0 = 0.f, a1 = 0.f;
    int j = o0;
    for (; j + 1 < o1; j += 2) {
        int s0 = ssrc[j], s1 = ssrc[j + 1];
        unsigned int v0 = *(const unsigned int*)(y1b + (long long)s0 * 64 + 2 * lane);
        unsigned int v1 = *(const unsigned int*)(y1b + (long long)s1 * 64 + 2 * lane);
        a0 += bf2f((unsigned short)v0) + bf2f((unsigned short)v1);
        a1 += bf2f((unsigned short)(v0 >> 16)) + bf2f((unsigned short)(v1 >> 16));
    }
    if (j < o1) {
        unsigned int v0 = *(const unsigned int*)(y1b + (long long)ssrc[j] * 64 + 2 * lane);
        a0 += bf2f((unsigned short)v0);
        a1 += bf2f((unsigned short)(v0 >> 16));
    }
    int deg = o1 - o0;
    float inv = (deg > 0) ? 1.f / (float)deg : 0.f;
    float2 zz = *(const float2*)(zbuf + (long long)node * 64 + 2 * lane);
    float2 o;
    o.x = fmaxf(a0 * inv + zz.x, 0.f);
    o.y = fmaxf(a1 * inv + zz.y, 0.f);
    *(float2*)(out + (long long)node * 64 + 2 * lane) = o;
}

// ---------------- MFMA GEMM: A[NROWS][128]bf16 @ Bt[128][128]bf16 ----------------
template<int MODE>
__global__ __launch_bounds__(256) void k_gemm(
    const unsigned short* __restrict__ A,
    const unsigned short* __restrict__ Bt,
    const float* __restrict__ bias,
    unsigned short* __restrict__ outb,
    float* __restrict__ outf) {
    __shared__ unsigned short lds[2 * 128 * 128];  // A tile then B, 64 KB
    __shared__ float sBias[128];
    const int tid = threadIdx.x;
    const int wid = tid >> 6;
    const int lane = tid & 63;

    // MODE 1 epilogue reads sBias[col] with col in [64,128) -> store b2 there.
    if (tid < 128) sBias[tid] = (MODE == 0) ? bias[tid] : ((tid >= 64) ? bias[tid - 64] : 0.f);

    const char* Ag = (const char*)(A + (long long)blockIdx.x * 128 * 128);
    const char* Bg = (const char*)Bt;
    char* ldsc = (char*)lds;
    #pragma unroll
    for (int j = 0; j < 8; ++j) {
        int g = wid * 512 + j * 64 + lane;        // granule (16B) index in [0,2048)
        int gs = g ^ ((g >> 4) & 7);              // pre-swizzled source granule
        GLOAD_LDS16(Ag + (long long)gs * 16, ldsc + (wid * 8192 + j * 1024));
        GLOAD_LDS16(Bg + (long long)gs * 16, ldsc + 32768 + (wid * 8192 + j * 1024));
    }
    __syncthreads();

    const int rA = lane & 15;
    const int kq = lane >> 4;                     // 0..3
    f32x4 acc[2][8] = {};

    #pragma unroll
    for (int ks = 0; ks < 4; ++ks) {
        const int kbyte = ks * 64 + kq * 16;
        bf16x8 a[2], b[8];
        #pragma unroll
        for (int m = 0; m < 2; ++m) {
            int row = wid * 32 + m * 16 + rA;
            int byte = row * 256 + (kbyte ^ ((row & 7) << 4));
            a[m] = *(const bf16x8*)(ldsc + byte);
        }
        #pragma unroll
        for (int n = 0; n < 8; ++n) {
            int row = n * 16 + rA;
            int byte = 32768 + row * 256 + (kbyte ^ ((row & 7) << 4));
            b[n] = *(const bf16x8*)(ldsc + byte);
        }
        #pragma unroll
        for (int m = 0; m < 2; ++m)
            #pragma unroll
            for (int n = 0; n < 8; ++n)
                acc[m][n] = __builtin_amdgcn_mfma_f32_16x16x32_bf16(a[m], b[n], acc[m][n], 0, 0, 0);
    }

    #pragma unroll
    for (int m = 0; m < 2; ++m) {
        #pragma unroll
        for (int n = 0; n < 8; ++n) {
            int col = n * 16 + rA;
            long long row0 = (long long)blockIdx.x * 128 + wid * 32 + m * 16 + kq * 4;
            #pragma unroll
            for (int r = 0; r < 4; ++r) {
                long long row = row0 + r;
                if (row < NN) {
                    float v = acc[m][n][r];
                    if (MODE == 0) {
                        v = fmaxf(v + sBias[col], 0.f);
                        outb[row * 128 + col] = f2bf(v);
                    } else {
                        if (col < 64) outb[row * 64 + col] = f2bf(v);
                        else          outf[row * 64 + (col - 64)] = v + sBias[col];
                    }
                }
            }
        }
    }
}

extern "C" void kernel_launch(void* const* d_in, const int* in_sizes, int n_in,
                              void* d_out, int out_size, void* d_ws, size_t ws_size,
                              hipStream_t stream) {
    const float* x   = (const float*)d_in[0];
    const int*   ei  = (const int*)d_in[1];
    const int*   src = ei;
    const int*   dst = ei + NE;
    const float* W1l = (const float*)d_in[2];
    const float* b1  = (const float*)d_in[3];
    const float* W1r = (const float*)d_in[4];
    const float* W2l = (const float*)d_in[5];
    const float* b2  = (const float*)d_in[6];
    const float* W2r = (const float*)d_in[7];
    float* out = (float*)d_out;

    // workspace layout (bytes):
    //   [0,         400640)     off     int[NN+1]
    //   [400640,    6800640)    ssrc    int[NE]
    //   [6800640,   6850688)    bin_cnt int[NBIN*16]    <- memset
    //   [6850688,   6852736)    bsum    int[512]
    //   [6852736,   6854784)    boff    int[512]
    //   [6854912,   32479488)   pairs   int2[NBIN*CAP]
    //   [32479488,  58104064)   Axcat   bf16[NROWS][128]
    //   [58104064,  83728640)   h1b     bf16[NROWS][128]
    //   [83728640,  96528640)   y1b     bf16[NN][64]
    //   [96528640,  122128640)  zbuf    f32 [NN][64]
    //   [122128640, 122161408)  Wc1     bf16[128][128]
    //   [122161408, 122194176)  Wc2     bf16[128][128]
    //   [122194176, 122594176)  cnt     int[NN]
    char* ws = (char*)d_ws;
    int*   off     = (int*)ws;
    int*   ssrc    = (int*)(ws + 400640);
    int*   bin_cnt = (int*)(ws + 6800640);
    int*   bsum    = (int*)(ws + 6850688);
    int*   boff    = (int*)(ws + 6852736);
    int2*  pairs   = (int2*)(ws + 6854912);
    unsigned short* Axcat = (unsigned short*)(ws + 32479488);
    unsigned short* h1b   = (unsigned short*)(ws + 58104064);
    unsigned short* y1b   = (unsigned short*)(ws + 83728640);
    float*          zbuf  = (float*)(ws + 96528640);
    unsigned short* Wc1   = (unsigned short*)(ws + 122128640);
    unsigned short* Wc2   = (unsigned short*)(ws + 122161408);
    int*   cnt     = (int*)(ws + 122194176);

    hipMemsetAsync(bin_cnt, 0, NBIN * 16 * 4, stream);

    k_binA<<<(NE + 255) / 256, 256, 0, stream>>>(src, dst, bin_cnt, pairs);
    k_binCount<<<NBIN, 256, 0, stream>>>(pairs, bin_cnt, cnt);
    k_scan_blk<<<NB, 256, 0, stream>>>(cnt, off, bsum);
    k_scan_top<<<1, 512, 0, stream>>>(bsum, boff);
    k_scan_add<<<NB, 256, 0, stream>>>(off, boff);
    k_binPlace<<<NBIN, 256, 0, stream>>>(pairs, bin_cnt, off, ssrc);
    k_prep_w<<<1, 256, 0, stream>>>(W1l, W1r, W2l, W2r, Wc1, Wc2);
    k_cvt_x<<<(NN * 32 + 255) / 256, 256, 0, stream>>>(x, Axcat);
    k_gather_x<<<(NN / 2 * 64 + 255) / 256, 256, 0, stream>>>(ssrc, off, Axcat);
    k_gemm<0><<<NROWS / 128, 256, 0, stream>>>(Axcat, Wc1, b1, h1b, nullptr);
    k_gemm<1><<<NROWS / 128, 256, 0, stream>>>(h1b, Wc2, b2, y1b, zbuf);
    k_gather_out<<<(NN / 2 * 64 + 255) / 256, 256, 0, stream>>>(ssrc, off, y1b, zbuf, out);
}

// Round 8
// 386.984 us; speedup vs baseline: 4.2638x; 1.0259x over previous
//
#include <hip/hip_runtime.h>
#include <hip/hip_bf16.h>

#define NN 100000
#define NE 1600000
#define NROWS 100096   // 782 * 128, padded row count for GEMM tiles
#define NBIN 782       // ceil(NN/128) bins of 128 nodes
#define CAPS 512       // max edges per (sub,bin): mean 256, sigma 16
#define CSTRIDE 1024   // bin_cnt per-sub stride (ints) - keeps subs on separate lines

typedef short bf16x8 __attribute__((ext_vector_type(8)));
typedef float f32x4 __attribute__((ext_vector_type(4)));

static __device__ __forceinline__ unsigned short f2bf(float f) {
    __hip_bfloat16 h = __float2bfloat16(f);
    return *reinterpret_cast<unsigned short*>(&h);
}
static __device__ __forceinline__ float bf2f(unsigned short u) {
    union { unsigned int i; float f; } v;
    v.i = ((unsigned int)u) << 16;
    return v.f;
}

#define GLOAD_LDS16(g, l) \
    __builtin_amdgcn_global_load_lds((const __attribute__((address_space(1))) void*)(g), \
                                     (__attribute__((address_space(3))) void*)(l), 16, 0, 0)

// ---------------- pass A: bin edges by dst>>7 into XCD-private sub-bins ----------------
// sub = blockIdx&7 (round-robins with XCD) -> frontier lines stay in one XCD's L2.
// payload packed: (src<<7) | (dst&127), src < 2^17.
__global__ void k_binA(const int* __restrict__ src, const int* __restrict__ dst,
                       int* __restrict__ bin_cnt, unsigned int* __restrict__ pairs) {
    int e = blockIdx.x * 256 + threadIdx.x;
    int sub = blockIdx.x & 7;
    if (e < NE) {
        int s = src[e], d = dst[e];
        int b = d >> 7;
        int p = atomicAdd(&bin_cnt[sub * CSTRIDE + b], 1);
        if (p < CAPS)
            pairs[((long long)(sub * NBIN + b)) * CAPS + p] = ((unsigned int)s << 7) | (unsigned int)(d & 127);
    }
}

// ---------------- scan of 782 bin totals (single block) ----------------
__global__ __launch_bounds__(1024) void k_scan_bins(const int* __restrict__ bin_cnt,
                                                    int* __restrict__ bbase,
                                                    int* __restrict__ off) {
    __shared__ int sh[1024];
    int t = threadIdx.x;
    int v = 0;
    if (t < NBIN) {
        #pragma unroll
        for (int s = 0; s < 8; ++s) v += min(bin_cnt[s * CSTRIDE + t], CAPS);
    }
    sh[t] = v;
    __syncthreads();
    for (int d = 1; d < 1024; d <<= 1) {
        int add = (t >= d) ? sh[t - d] : 0;
        __syncthreads();
        sh[t] += add;
        __syncthreads();
    }
    if (t < NBIN) bbase[t] = sh[t] - v;  // exclusive
    if (t == 0) off[NN] = NE;
}

// ---------------- per-bin: count -> offsets -> LDS scatter -> sequential dump ----------------
__global__ __launch_bounds__(256) void k_binPlace(const unsigned int* __restrict__ pairs,
                                                  const int* __restrict__ bin_cnt,
                                                  const int* __restrict__ bbase,
                                                  int* __restrict__ off,
                                                  int* __restrict__ ssrc) {
    __shared__ int sbuf[4096];
    __shared__ int lcnt[128];
    __shared__ int sstart[128];
    __shared__ int lcur[128];
    __shared__ int sscan[128];
    int b = blockIdx.x, t = threadIdx.x;
    if (t < 128) { lcnt[t] = 0; lcur[t] = 0; }
    __syncthreads();
    // pass 1: per-node counts
    for (int s = 0; s < 8; ++s) {
        int n = min(bin_cnt[s * CSTRIDE + b], CAPS);
        const unsigned int* pp = pairs + ((long long)(s * NBIN + b)) * CAPS;
        for (int i = t; i < n; i += 256)
            atomicAdd(&lcnt[pp[i] & 127], 1);
    }
    __syncthreads();
    // exclusive scan of lcnt[128]
    int vv = (t < 128) ? lcnt[t] : 0;
    if (t < 128) sscan[t] = vv;
    __syncthreads();
    for (int d = 1; d < 128; d <<= 1) {
        int add = (t >= d && t < 128) ? sscan[t - d] : 0;
        __syncthreads();
        if (t < 128) sscan[t] += add;
        __syncthreads();
    }
    if (t < 128) {
        sstart[t] = sscan[t] - vv;
        int node = b * 128 + t;
        if (node < NN) off[node] = bbase[b] + sstart[t];
    }
    __syncthreads();
    // pass 2: scatter into LDS
    for (int s = 0; s < 8; ++s) {
        int n = min(bin_cnt[s * CSTRIDE + b], CAPS);
        const unsigned int* pp = pairs + ((long long)(s * NBIN + b)) * CAPS;
        for (int i = t; i < n; i += 256) {
            unsigned int p = pp[i];
            int dl = p & 127;
            int lp = atomicAdd(&lcur[dl], 1);
            sbuf[sstart[dl] + lp] = (int)(p >> 7);
        }
    }
    __syncthreads();
    int len = sscan[127];
    int base = bbase[b];
    for (int i = t; i < len; i += 256)
        ssrc[base + i] = sbuf[i];
}

// ---------------- weight prep: bf16, N-major (B^T) concatenated ----------------
__global__ __launch_bounds__(256) void k_prep_w(
    const float* __restrict__ W1l, const float* __restrict__ W1r,
    const float* __restrict__ W2l, const float* __restrict__ W2r,
    unsigned short* __restrict__ Wcat1t, unsigned short* __restrict__ Wcat2t) {
    for (int i = threadIdx.x; i < 128 * 128; i += 256) {
        int n = i >> 7, k = i & 127;
        float v1 = (k < 64) ? W1l[k * 128 + n] : W1r[(k - 64) * 128 + n];
        Wcat1t[i] = f2bf(v1);
        float v2 = (n < 64) ? W2l[k * 64 + n] : W2r[k * 64 + (n - 64)];
        Wcat2t[i] = f2bf(v2);
    }
}

// ---------------- convert x -> bf16 into Axcat[:,64:128] ----------------
__global__ __launch_bounds__(256) void k_cvt_x(const float* __restrict__ x,
                                               unsigned short* __restrict__ Axcat) {
    int idx = blockIdx.x * blockDim.x + threadIdx.x;  // node*32 + f2
    if (idx >= NN * 32) return;
    int node = idx >> 5, f2 = idx & 31;
    float2 v = *(const float2*)(x + (long long)node * 64 + 2 * f2);
    unsigned int p = (unsigned int)f2bf(v.x) | ((unsigned int)f2bf(v.y) << 16);
    *(unsigned int*)(Axcat + (long long)node * 128 + 64 + 2 * f2) = p;
}

// ---------------- gather-mean of bf16 x-half -> bf16 mean1-half (64 feats) ----------------
__global__ __launch_bounds__(256) void k_gather_x(const int* __restrict__ ssrc,
                                                  const int* __restrict__ off,
                                                  unsigned short* __restrict__ Axcat) {
    int wv = (blockIdx.x * blockDim.x + threadIdx.x) >> 6;
    int half = (threadIdx.x >> 5) & 1;
    int lane = threadIdx.x & 31;
    int node = wv * 2 + half;
    if (node >= NN) return;
    int o0 = off[node], o1 = off[node + 1];
    float a0 = 0.f, a1 = 0.f;
    int j = o0;
    for (; j + 1 < o1; j += 2) {
        int s0 = ssrc[j], s1 = ssrc[j + 1];
        unsigned int v0 = *(const unsigned int*)(Axcat + (long long)s0 * 128 + 64 + 2 * lane);
        unsigned int v1 = *(const unsigned int*)(Axcat + (long long)s1 * 128 + 64 + 2 * lane);
        a0 += bf2f((unsigned short)v0) + bf2f((unsigned short)v1);
        a1 += bf2f((unsigned short)(v0 >> 16)) + bf2f((unsigned short)(v1 >> 16));
    }
    if (j < o1) {
        unsigned int v0 = *(const unsigned int*)(Axcat + (long long)ssrc[j] * 128 + 64 + 2 * lane);
        a0 += bf2f((unsigned short)v0);
        a1 += bf2f((unsigned short)(v0 >> 16));
    }
    int deg = o1 - o0;
    float inv = (deg > 0) ? 1.f / (float)deg : 0.f;
    unsigned int p = (unsigned int)f2bf(a0 * inv) | ((unsigned int)f2bf(a1 * inv) << 16);
    *(unsigned int*)(Axcat + (long long)node * 128 + 2 * lane) = p;
}

// ---------------- gather-mean of bf16 y1 + z + relu -> out ----------------
__global__ __launch_bounds__(256) void k_gather_out(const int* __restrict__ ssrc,
                                                    const int* __restrict__ off,
                                                    const unsigned short* __restrict__ y1b,
                                                    const float* __restrict__ zbuf,
                                                    float* __restrict__ out) {
    int wv = (blockIdx.x * blockDim.x + threadIdx.x) >> 6;
    int half = (threadIdx.x >> 5) & 1;
    int lane = threadIdx.x & 31;
    int node = wv * 2 + half;
    if (node >= NN) return;
    int o0 = off[node], o1 = off[node + 1];
    float a0 = 0.f, a1 = 0.f;
    int j = o0;
    for (; j + 1 < o1; j += 2) {
        int s0 = ssrc[j], s1 = ssrc[j + 1];
        unsigned int v0 = *(const unsigned int*)(y1b + (long long)s0 * 64 + 2 * lane);
        unsigned int v1 = *(const unsigned int*)(y1b + (long long)s1 * 64 + 2 * lane);
        a0 += bf2f((unsigned short)v0) + bf2f((unsigned short)v1);
        a1 += bf2f((unsigned short)(v0 >> 16)) + bf2f((unsigned short)(v1 >> 16));
    }
    if (j < o1) {
        unsigned int v0 = *(const unsigned int*)(y1b + (long long)ssrc[j] * 64 + 2 * lane);
        a0 += bf2f((unsigned short)v0);
        a1 += bf2f((unsigned short)(v0 >> 16));
    }
    int deg = o1 - o0;
    float inv = (deg > 0) ? 1.f / (float)deg : 0.f;
    float2 zz = *(const float2*)(zbuf + (long long)node * 64 + 2 * lane);
    float2 o;
    o.x = fmaxf(a0 * inv + zz.x, 0.f);
    o.y = fmaxf(a1 * inv + zz.y, 0.f);
    *(float2*)(out + (long long)node * 64 + 2 * lane) = o;
}

// ---------------- MFMA GEMM: A[NROWS][128]bf16 @ Bt[128][128]bf16 ----------------
template<int MODE>
__global__ __launch_bounds__(256) void k_gemm(
    const unsigned short* __restrict__ A,
    const unsigned short* __restrict__ Bt,
    const float* __restrict__ bias,
    unsigned short* __restrict__ outb,
    float* __restrict__ outf) {
    __shared__ unsigned short lds[2 * 128 * 128];  // A tile then B, 64 KB
    __shared__ float sBias[128];
    const int tid = threadIdx.x;
    const int wid = tid >> 6;
    const int lane = tid & 63;

    // MODE 1 epilogue reads sBias[col] with col in [64,128) -> store b2 there.
    if (tid < 128) sBias[tid] = (MODE == 0) ? bias[tid] : ((tid >= 64) ? bias[tid - 64] : 0.f);

    const char* Ag = (const char*)(A + (long long)blockIdx.x * 128 * 128);
    const char* Bg = (const char*)Bt;
    char* ldsc = (char*)lds;
    #pragma unroll
    for (int j = 0; j < 8; ++j) {
        int g = wid * 512 + j * 64 + lane;        // granule (16B) index in [0,2048)
        int gs = g ^ ((g >> 4) & 7);              // pre-swizzled source granule
        GLOAD_LDS16(Ag + (long long)gs * 16, ldsc + (wid * 8192 + j * 1024));
        GLOAD_LDS16(Bg + (long long)gs * 16, ldsc + 32768 + (wid * 8192 + j * 1024));
    }
    __syncthreads();

    const int rA = lane & 15;
    const int kq = lane >> 4;                     // 0..3
    f32x4 acc[2][8] = {};

    #pragma unroll
    for (int ks = 0; ks < 4; ++ks) {
        const int kbyte = ks * 64 + kq * 16;
        bf16x8 a[2], b[8];
        #pragma unroll
        for (int m = 0; m < 2; ++m) {
            int row = wid * 32 + m * 16 + rA;
            int byte = row * 256 + (kbyte ^ ((row & 7) << 4));
            a[m] = *(const bf16x8*)(ldsc + byte);
        }
        #pragma unroll
        for (int n = 0; n < 8; ++n) {
            int row = n * 16 + rA;
            int byte = 32768 + row * 256 + (kbyte ^ ((row & 7) << 4));
            b[n] = *(const bf16x8*)(ldsc + byte);
        }
        #pragma unroll
        for (int m = 0; m < 2; ++m)
            #pragma unroll
            for (int n = 0; n < 8; ++n)
                acc[m][n] = __builtin_amdgcn_mfma_f32_16x16x32_bf16(a[m], b[n], acc[m][n], 0, 0, 0);
    }

    #pragma unroll
    for (int m = 0; m < 2; ++m) {
        #pragma unroll
        for (int n = 0; n < 8; ++n) {
            int col = n * 16 + rA;
            long long row0 = (long long)blockIdx.x * 128 + wid * 32 + m * 16 + kq * 4;
            #pragma unroll
            for (int r = 0; r < 4; ++r) {
                long long row = row0 + r;
                if (row < NN) {
                    float v = acc[m][n][r];
                    if (MODE == 0) {
                        v = fmaxf(v + sBias[col], 0.f);
                        outb[row * 128 + col] = f2bf(v);
                    } else {
                        if (col < 64) outb[row * 64 + col] = f2bf(v);
                        else          outf[row * 64 + (col - 64)] = v + sBias[col];
                    }
                }
            }
        }
    }
}

extern "C" void kernel_launch(void* const* d_in, const int* in_sizes, int n_in,
                              void* d_out, int out_size, void* d_ws, size_t ws_size,
                              hipStream_t stream) {
    const float* x   = (const float*)d_in[0];
    const int*   ei  = (const int*)d_in[1];
    const int*   src = ei;
    const int*   dst = ei + NE;
    const float* W1l = (const float*)d_in[2];
    const float* b1  = (const float*)d_in[3];
    const float* W1r = (const float*)d_in[4];
    const float* W2l = (const float*)d_in[5];
    const float* b2  = (const float*)d_in[6];
    const float* W2r = (const float*)d_in[7];
    float* out = (float*)d_out;

    // workspace layout (bytes):
    //   [0,         400640)     off     int[NN+1]
    //   [400640,    6800640)    ssrc    int[NE]
    //   [6800640,   6833408)    bin_cnt int[8*CSTRIDE]   <- memset
    //   [6833408,   6837504)    bbase   int[1024]
    //   [6837504,   19649792)   pairs   uint[8*NBIN*CAPS]
    //   [19649792,  45274368)   Axcat   bf16[NROWS][128]
    //   [45274368,  70898944)   h1b     bf16[NROWS][128]
    //   [70898944,  83698944)   y1b     bf16[NN][64]
    //   [83698944,  109298944)  zbuf    f32 [NN][64]
    //   [109298944, 109331712)  Wc1     bf16[128][128]
    //   [109331712, 109364480)  Wc2     bf16[128][128]
    char* ws = (char*)d_ws;
    int*   off     = (int*)ws;
    int*   ssrc    = (int*)(ws + 400640);
    int*   bin_cnt = (int*)(ws + 6800640);
    int*   bbase   = (int*)(ws + 6833408);
    unsigned int* pairs = (unsigned int*)(ws + 6837504);
    unsigned short* Axcat = (unsigned short*)(ws + 19649792);
    unsigned short* h1b   = (unsigned short*)(ws + 45274368);
    unsigned short* y1b   = (unsigned short*)(ws + 70898944);
    float*          zbuf  = (float*)(ws + 83698944);
    unsigned short* Wc1   = (unsigned short*)(ws + 109298944);
    unsigned short* Wc2   = (unsigned short*)(ws + 109331712);

    hipMemsetAsync(bin_cnt, 0, 8 * CSTRIDE * 4, stream);

    k_binA<<<NE / 256, 256, 0, stream>>>(src, dst, bin_cnt, pairs);
    k_scan_bins<<<1, 1024, 0, stream>>>(bin_cnt, bbase, off);
    k_binPlace<<<NBIN, 256, 0, stream>>>(pairs, bin_cnt, bbase, off, ssrc);
    k_prep_w<<<1, 256, 0, stream>>>(W1l, W1r, W2l, W2r, Wc1, Wc2);
    k_cvt_x<<<(NN * 32 + 255) / 256, 256, 0, stream>>>(x, Axcat);
    k_gather_x<<<(NN / 2 * 64 + 255) / 256, 256, 0, stream>>>(ssrc, off, Axcat);
    k_gemm<0><<<NROWS / 128, 256, 0, stream>>>(Axcat, Wc1, b1, h1b, nullptr);
    k_gemm<1><<<NROWS / 128, 256, 0, stream>>>(h1b, Wc2, b2, y1b, zbuf);
    k_gather_out<<<(NN / 2 * 64 + 255) / 256, 256, 0, stream>>>(ssrc, off, y1b, zbuf, out);
}

// Round 9
// 301.413 us; speedup vs baseline: 5.4743x; 1.2839x over previous
//
#include <hip/hip_runtime.h>
#include <hip/hip_bf16.h>

#define NN 100000
#define NE 1600000
#define NROWS 100096   // 782 * 128, padded row count for GEMM tiles
#define NBIN2 196      // ceil(NN/512) bins of 512 nodes (dst>>9)
#define NCHUNK 256     // edge chunks (= placement blocks)
#define EPB 6250       // edges per chunk (256*6250 = NE exactly)
#define CAPBIN 13312   // padded per-bin capacity (mean 8163 + pad <=3840 + slack)
#define SENT 0xFFFFFFFFu

typedef short bf16x8 __attribute__((ext_vector_type(8)));
typedef float f32x4 __attribute__((ext_vector_type(4)));

static __device__ __forceinline__ unsigned short f2bf(float f) {
    __hip_bfloat16 h = __float2bfloat16(f);
    return *reinterpret_cast<unsigned short*>(&h);
}
static __device__ __forceinline__ float bf2f(unsigned short u) {
    union { unsigned int i; float f; } v;
    v.i = ((unsigned int)u) << 16;
    return v.f;
}

#define GLOAD_LDS16(g, l) \
    __builtin_amdgcn_global_load_lds((const __attribute__((address_space(1))) void*)(g), \
                                     (__attribute__((address_space(3))) void*)(l), 16, 0, 0)

// ---------------- A1: per-chunk histogram over 196 bins ----------------
__global__ __launch_bounds__(256) void k_hist(const int* __restrict__ dst,
                                              int* __restrict__ hist) {
    __shared__ int lcnt[NBIN2];
    int k = blockIdx.x, t = threadIdx.x;
    if (t < NBIN2) lcnt[t] = 0;
    __syncthreads();
    int base = k * EPB;
    for (int i = t; i < EPB; i += 256) {
        int e = base + i;
        if (e < NE) atomicAdd(&lcnt[dst[e] >> 9], 1);
    }
    __syncthreads();
    if (t < NBIN2) hist[t * NCHUNK + k] = lcnt[t];   // [bin][chunk]
}

// ---------------- A2a: per-bin scan over chunks (padded to 16) ----------------
__global__ __launch_bounds__(256) void k_scanA2a(const int* __restrict__ hist,
                                                 int* __restrict__ pbase,
                                                 int* __restrict__ ptot,
                                                 int* __restrict__ ttot) {
    __shared__ int shp[256];
    __shared__ int shv[256];
    int b = blockIdx.x, t = threadIdx.x;
    int v = hist[b * NCHUNK + t];
    int pv = (v + 15) & ~15;
    shp[t] = pv; shv[t] = v;
    __syncthreads();
    for (int d = 1; d < 256; d <<= 1) {
        int a1 = (t >= d) ? shp[t - d] : 0;
        int a2 = (t >= d) ? shv[t - d] : 0;
        __syncthreads();
        shp[t] += a1; shv[t] += a2;
        __syncthreads();
    }
    pbase[b * NCHUNK + t] = shp[t] - pv;   // exclusive padded base
    if (t == 255) { ptot[b] = shp[255]; ttot[b] = shv[255]; }
}

// ---------------- A2b: scan of 196 true bin totals -> bbase ----------------
__global__ __launch_bounds__(256) void k_scanA2b(const int* __restrict__ ttot,
                                                 int* __restrict__ bbase,
                                                 int* __restrict__ off) {
    __shared__ int sh[256];
    int t = threadIdx.x;
    int v = (t < NBIN2) ? ttot[t] : 0;
    sh[t] = v;
    __syncthreads();
    for (int d = 1; d < 256; d <<= 1) {
        int add = (t >= d) ? sh[t - d] : 0;
        __syncthreads();
        sh[t] += add;
        __syncthreads();
    }
    if (t < NBIN2) bbase[t] = sh[t] - v;
    if (t == 0) off[NN] = NE;
}

// ---------------- A3: deterministic placement (no global atomics) ----------------
// pairs[b*CAPBIN + pbase[b][k] + local_pos] = (src<<9)|(dst&511); pad to 16 w/ SENT.
// Every 64B line of pairs is written entirely by one block -> writeback == payload.
__global__ __launch_bounds__(256) void k_placeA3(const int* __restrict__ src,
                                                 const int* __restrict__ dst,
                                                 const int* __restrict__ pbase,
                                                 unsigned int* __restrict__ pairs) {
    __shared__ int sbase[NBIN2];
    __shared__ int lcur[NBIN2];
    int k = blockIdx.x, t = threadIdx.x;
    if (t < NBIN2) { sbase[t] = pbase[t * NCHUNK + k]; lcur[t] = 0; }
    __syncthreads();
    int base = k * EPB;
    for (int i = t; i < EPB; i += 256) {
        int e = base + i;
        if (e < NE) {
            int s = src[e], d = dst[e];
            int b = d >> 9;
            int pos = atomicAdd(&lcur[b], 1);
            pairs[(long long)b * CAPBIN + sbase[b] + pos] =
                ((unsigned int)s << 9) | (unsigned int)(d & 511);
        }
    }
    __syncthreads();
    // sentinel-pad each (chunk,bin) range to its 16-aligned end
    for (int b = t; b < NBIN2; b += 256) {
        int cnt = lcur[b];
        int end = sbase[b] + cnt;
        int pend = sbase[b] + ((cnt + 15) & ~15);
        for (int i = end; i < pend; ++i)
            pairs[(long long)b * CAPBIN + i] = SENT;
    }
}

// ---------------- B: per-bin count -> offsets -> LDS scatter -> sequential dump ----------------
__global__ __launch_bounds__(512) void k_binPlace(const unsigned int* __restrict__ pairs,
                                                  const int* __restrict__ ptot,
                                                  const int* __restrict__ bbase,
                                                  int* __restrict__ off,
                                                  int* __restrict__ ssrc) {
    __shared__ int sbuf[9472];
    __shared__ int lcnt[512];
    __shared__ int sstart[512];
    __shared__ int lcur[512];
    __shared__ int sscan[512];
    int b = blockIdx.x, t = threadIdx.x;
    lcnt[t] = 0; lcur[t] = 0;
    __syncthreads();
    int n = ptot[b];
    const unsigned int* pp = pairs + (long long)b * CAPBIN;
    // pass 1: per-node counts
    for (int i = t; i < n; i += 512) {
        unsigned int p = pp[i];
        if (p != SENT) atomicAdd(&lcnt[p & 511], 1);
    }
    __syncthreads();
    // exclusive scan of lcnt[512]
    int vv = lcnt[t];
    sscan[t] = vv;
    __syncthreads();
    for (int d = 1; d < 512; d <<= 1) {
        int add = (t >= d) ? sscan[t - d] : 0;
        __syncthreads();
        sscan[t] += add;
        __syncthreads();
    }
    sstart[t] = sscan[t] - vv;
    int node = b * 512 + t;
    if (node < NN) off[node] = bbase[b] + sstart[t];
    __syncthreads();
    // pass 2: scatter into LDS
    for (int i = t; i < n; i += 512) {
        unsigned int p = pp[i];
        if (p != SENT) {
            int dl = p & 511;
            int lp = atomicAdd(&lcur[dl], 1);
            sbuf[sstart[dl] + lp] = (int)(p >> 9);
        }
    }
    __syncthreads();
    int len = sscan[511];
    int base = bbase[b];
    for (int i = t; i < len; i += 512)
        ssrc[base + i] = sbuf[i];
}

// ---------------- weight prep: bf16, N-major (B^T) concatenated ----------------
__global__ __launch_bounds__(256) void k_prep_w(
    const float* __restrict__ W1l, const float* __restrict__ W1r,
    const float* __restrict__ W2l, const float* __restrict__ W2r,
    unsigned short* __restrict__ Wcat1t, unsigned short* __restrict__ Wcat2t) {
    for (int i = threadIdx.x; i < 128 * 128; i += 256) {
        int n = i >> 7, k = i & 127;
        float v1 = (k < 64) ? W1l[k * 128 + n] : W1r[(k - 64) * 128 + n];
        Wcat1t[i] = f2bf(v1);
        float v2 = (n < 64) ? W2l[k * 64 + n] : W2r[k * 64 + (n - 64)];
        Wcat2t[i] = f2bf(v2);
    }
}

// ---------------- convert x -> bf16 into Axcat[:,64:128] ----------------
__global__ __launch_bounds__(256) void k_cvt_x(const float* __restrict__ x,
                                               unsigned short* __restrict__ Axcat) {
    int idx = blockIdx.x * blockDim.x + threadIdx.x;  // node*32 + f2
    if (idx >= NN * 32) return;
    int node = idx >> 5, f2 = idx & 31;
    float2 v = *(const float2*)(x + (long long)node * 64 + 2 * f2);
    unsigned int p = (unsigned int)f2bf(v.x) | ((unsigned int)f2bf(v.y) << 16);
    *(unsigned int*)(Axcat + (long long)node * 128 + 64 + 2 * f2) = p;
}

// ---------------- gather-mean of bf16 x-half -> bf16 mean1-half (64 feats) ----------------
__global__ __launch_bounds__(256) void k_gather_x(const int* __restrict__ ssrc,
                                                  const int* __restrict__ off,
                                                  unsigned short* __restrict__ Axcat) {
    int wv = (blockIdx.x * blockDim.x + threadIdx.x) >> 6;
    int half = (threadIdx.x >> 5) & 1;
    int lane = threadIdx.x & 31;
    int node = wv * 2 + half;
    if (node >= NN) return;
    int o0 = off[node], o1 = off[node + 1];
    float a0 = 0.f, a1 = 0.f;
    int j = o0;
    for (; j + 1 < o1; j += 2) {
        int s0 = ssrc[j], s1 = ssrc[j + 1];
        unsigned int v0 = *(const unsigned int*)(Axcat + (long long)s0 * 128 + 64 + 2 * lane);
        unsigned int v1 = *(const unsigned int*)(Axcat + (long long)s1 * 128 + 64 + 2 * lane);
        a0 += bf2f((unsigned short)v0) + bf2f((unsigned short)v1);
        a1 += bf2f((unsigned short)(v0 >> 16)) + bf2f((unsigned short)(v1 >> 16));
    }
    if (j < o1) {
        unsigned int v0 = *(const unsigned int*)(Axcat + (long long)ssrc[j] * 128 + 64 + 2 * lane);
        a0 += bf2f((unsigned short)v0);
        a1 += bf2f((unsigned short)(v0 >> 16));
    }
    int deg = o1 - o0;
    float inv = (deg > 0) ? 1.f / (float)deg : 0.f;
    unsigned int p = (unsigned int)f2bf(a0 * inv) | ((unsigned int)f2bf(a1 * inv) << 16);
    *(unsigned int*)(Axcat + (long long)node * 128 + 2 * lane) = p;
}

// ---------------- gather-mean of bf16 y1 + z + relu -> out ----------------
__global__ __launch_bounds__(256) void k_gather_out(const int* __restrict__ ssrc,
                                                    const int* __restrict__ off,
                                                    const unsigned short* __restrict__ y1b,
                                                    const float* __restrict__ zbuf,
                                                    float* __restrict__ out) {
    int wv = (blockIdx.x * blockDim.x + threadIdx.x) >> 6;
    int half = (threadIdx.x >> 5) & 1;
    int lane = threadIdx.x & 31;
    int node = wv * 2 + half;
    if (node >= NN) return;
    int o0 = off[node], o1 = off[node + 1];
    float a0 = 0.f, a1 = 0.f;
    int j = o0;
    for (; j + 1 < o1; j += 2) {
        int s0 = ssrc[j], s1 = ssrc[j + 1];
        unsigned int v0 = *(const unsigned int*)(y1b + (long long)s0 * 64 + 2 * lane);
        unsigned int v1 = *(const unsigned int*)(y1b + (long long)s1 * 64 + 2 * lane);
        a0 += bf2f((unsigned short)v0) + bf2f((unsigned short)v1);
        a1 += bf2f((unsigned short)(v0 >> 16)) + bf2f((unsigned short)(v1 >> 16));
    }
    if (j < o1) {
        unsigned int v0 = *(const unsigned int*)(y1b + (long long)ssrc[j] * 64 + 2 * lane);
        a0 += bf2f((unsigned short)v0);
        a1 += bf2f((unsigned short)(v0 >> 16));
    }
    int deg = o1 - o0;
    float inv = (deg > 0) ? 1.f / (float)deg : 0.f;
    float2 zz = *(const float2*)(zbuf + (long long)node * 64 + 2 * lane);
    float2 o;
    o.x = fmaxf(a0 * inv + zz.x, 0.f);
    o.y = fmaxf(a1 * inv + zz.y, 0.f);
    *(float2*)(out + (long long)node * 64 + 2 * lane) = o;
}

// ---------------- MFMA GEMM: A[NROWS][128]bf16 @ Bt[128][128]bf16 ----------------
template<int MODE>
__global__ __launch_bounds__(256) void k_gemm(
    const unsigned short* __restrict__ A,
    const unsigned short* __restrict__ Bt,
    const float* __restrict__ bias,
    unsigned short* __restrict__ outb,
    float* __restrict__ outf) {
    __shared__ unsigned short lds[2 * 128 * 128];  // A tile then B, 64 KB
    __shared__ float sBias[128];
    const int tid = threadIdx.x;
    const int wid = tid >> 6;
    const int lane = tid & 63;

    // MODE 1 epilogue reads sBias[col] with col in [64,128) -> store b2 there.
    if (tid < 128) sBias[tid] = (MODE == 0) ? bias[tid] : ((tid >= 64) ? bias[tid - 64] : 0.f);

    const char* Ag = (const char*)(A + (long long)blockIdx.x * 128 * 128);
    const char* Bg = (const char*)Bt;
    char* ldsc = (char*)lds;
    #pragma unroll
    for (int j = 0; j < 8; ++j) {
        int g = wid * 512 + j * 64 + lane;        // granule (16B) index in [0,2048)
        int gs = g ^ ((g >> 4) & 7);              // pre-swizzled source granule
        GLOAD_LDS16(Ag + (long long)gs * 16, ldsc + (wid * 8192 + j * 1024));
        GLOAD_LDS16(Bg + (long long)gs * 16, ldsc + 32768 + (wid * 8192 + j * 1024));
    }
    __syncthreads();

    const int rA = lane & 15;
    const int kq = lane >> 4;                     // 0..3
    f32x4 acc[2][8] = {};

    #pragma unroll
    for (int ks = 0; ks < 4; ++ks) {
        const int kbyte = ks * 64 + kq * 16;
        bf16x8 a[2], b[8];
        #pragma unroll
        for (int m = 0; m < 2; ++m) {
            int row = wid * 32 + m * 16 + rA;
            int byte = row * 256 + (kbyte ^ ((row & 7) << 4));
            a[m] = *(const bf16x8*)(ldsc + byte);
        }
        #pragma unroll
        for (int n = 0; n < 8; ++n) {
            int row = n * 16 + rA;
            int byte = 32768 + row * 256 + (kbyte ^ ((row & 7) << 4));
            b[n] = *(const bf16x8*)(ldsc + byte);
        }
        #pragma unroll
        for (int m = 0; m < 2; ++m)
            #pragma unroll
            for (int n = 0; n < 8; ++n)
                acc[m][n] = __builtin_amdgcn_mfma_f32_16x16x32_bf16(a[m], b[n], acc[m][n], 0, 0, 0);
    }

    #pragma unroll
    for (int m = 0; m < 2; ++m) {
        #pragma unroll
        for (int n = 0; n < 8; ++n) {
            int col = n * 16 + rA;
            long long row0 = (long long)blockIdx.x * 128 + wid * 32 + m * 16 + kq * 4;
            #pragma unroll
            for (int r = 0; r < 4; ++r) {
                long long row = row0 + r;
                if (row < NN) {
                    float v = acc[m][n][r];
                    if (MODE == 0) {
                        v = fmaxf(v + sBias[col], 0.f);
                        outb[row * 128 + col] = f2bf(v);
                    } else {
                        if (col < 64) outb[row * 64 + col] = f2bf(v);
                        else          outf[row * 64 + (col - 64)] = v + sBias[col];
                    }
                }
            }
        }
    }
}

extern "C" void kernel_launch(void* const* d_in, const int* in_sizes, int n_in,
                              void* d_out, int out_size, void* d_ws, size_t ws_size,
                              hipStream_t stream) {
    const float* x   = (const float*)d_in[0];
    const int*   ei  = (const int*)d_in[1];
    const int*   src = ei;
    const int*   dst = ei + NE;
    const float* W1l = (const float*)d_in[2];
    const float* b1  = (const float*)d_in[3];
    const float* W1r = (const float*)d_in[4];
    const float* W2l = (const float*)d_in[5];
    const float* b2  = (const float*)d_in[6];
    const float* W2r = (const float*)d_in[7];
    float* out = (float*)d_out;

    // workspace layout (bytes), all buffers fully written before read (no memset):
    //   [0,         400640)     off    int[NN+1]
    //   [400640,    6800640)    ssrc   int[NE]
    //   [6800640,   7001344)    hist   int[NBIN2*NCHUNK]
    //   [7001344,   7202048)    pbase  int[NBIN2*NCHUNK]
    //   [7202048,   7203072)    ptot   int[256]
    //   [7203072,   7204096)    ttot   int[256]
    //   [7204096,   7205120)    bbase  int[256]
    //   [7205120,   17641728)   pairs  uint[NBIN2*CAPBIN]
    //   [17641728,  43266304)   Axcat  bf16[NROWS][128]
    //   [43266304,  68890880)   h1b    bf16[NROWS][128]
    //   [68890880,  81690880)   y1b    bf16[NN][64]
    //   [81690880,  107290880)  zbuf   f32 [NN][64]
    //   [107290880, 107323648)  Wc1    bf16[128][128]
    //   [107323648, 107356416)  Wc2    bf16[128][128]
    char* ws = (char*)d_ws;
    int*   off   = (int*)ws;
    int*   ssrc  = (int*)(ws + 400640);
    int*   hist  = (int*)(ws + 6800640);
    int*   pbase = (int*)(ws + 7001344);
    int*   ptot  = (int*)(ws + 7202048);
    int*   ttot  = (int*)(ws + 7203072);
    int*   bbase = (int*)(ws + 7204096);
    unsigned int* pairs = (unsigned int*)(ws + 7205120);
    unsigned short* Axcat = (unsigned short*)(ws + 17641728);
    unsigned short* h1b   = (unsigned short*)(ws + 43266304);
    unsigned short* y1b   = (unsigned short*)(ws + 68890880);
    float*          zbuf  = (float*)(ws + 81690880);
    unsigned short* Wc1   = (unsigned short*)(ws + 107290880);
    unsigned short* Wc2   = (unsigned short*)(ws + 107323648);

    k_hist<<<NCHUNK, 256, 0, stream>>>(dst, hist);
    k_scanA2a<<<NBIN2, 256, 0, stream>>>(hist, pbase, ptot, ttot);
    k_scanA2b<<<1, 256, 0, stream>>>(ttot, bbase, off);
    k_placeA3<<<NCHUNK, 256, 0, stream>>>(src, dst, pbase, pairs);
    k_binPlace<<<NBIN2, 512, 0, stream>>>(pairs, ptot, bbase, off, ssrc);
    k_prep_w<<<1, 256, 0, stream>>>(W1l, W1r, W2l, W2r, Wc1, Wc2);
    k_cvt_x<<<(NN * 32 + 255) / 256, 256, 0, stream>>>(x, Axcat);
    k_gather_x<<<(NN / 2 * 64 + 255) / 256, 256, 0, stream>>>(ssrc, off, Axcat);
    k_gemm<0><<<NROWS / 128, 256, 0, stream>>>(Axcat, Wc1, b1, h1b, nullptr);
    k_gemm<1><<<NROWS / 128, 256, 0, stream>>>(h1b, Wc2, b2, y1b, zbuf);
    k_gather_out<<<(NN / 2 * 64 + 255) / 256, 256, 0, stream>>>(ssrc, off, y1b, zbuf, out);
}

// Round 10
// 257.713 us; speedup vs baseline: 6.4026x; 1.1696x over previous
//
#include <hip/hip_runtime.h>
#include <hip/hip_bf16.h>

#define NN 100000
#define NE 1600000
#define NROWS 100096   // 782 * 128, padded row count for GEMM tiles
#define NBIN2 196      // ceil(NN/512) bins of 512 nodes (dst>>9)
#define NCHUNK 256     // edge chunks (= placement blocks)
#define EPB 6250       // edges per chunk (256*6250 = NE exactly)
#define CAPBIN 13312   // padded per-bin capacity (mean 8163 + pad <=3840 + slack)
#define SENT 0xFFFFFFFFu

typedef short bf16x8 __attribute__((ext_vector_type(8)));
typedef float f32x4 __attribute__((ext_vector_type(4)));

static __device__ __forceinline__ unsigned short f2bf(float f) {
    __hip_bfloat16 h = __float2bfloat16(f);
    return *reinterpret_cast<unsigned short*>(&h);
}
static __device__ __forceinline__ float bf2f(unsigned short u) {
    union { unsigned int i; float f; } v;
    v.i = ((unsigned int)u) << 16;
    return v.f;
}

#define GLOAD_LDS16(g, l) \
    __builtin_amdgcn_global_load_lds((const __attribute__((address_space(1))) void*)(g), \
                                     (__attribute__((address_space(3))) void*)(l), 16, 0, 0)

// ---------------- A1: per-chunk histogram over 196 bins ----------------
__global__ __launch_bounds__(256) void k_hist(const int* __restrict__ dst,
                                              int* __restrict__ hist) {
    __shared__ int lcnt[NBIN2];
    int k = blockIdx.x, t = threadIdx.x;
    if (t < NBIN2) lcnt[t] = 0;
    __syncthreads();
    int base = k * EPB;
    for (int i = t; i < EPB; i += 256) {
        int e = base + i;
        if (e < NE) atomicAdd(&lcnt[dst[e] >> 9], 1);
    }
    __syncthreads();
    if (t < NBIN2) hist[t * NCHUNK + k] = lcnt[t];   // [bin][chunk]
}

// ---------------- A2a: per-bin scan over chunks (padded to 16) ----------------
__global__ __launch_bounds__(256) void k_scanA2a(const int* __restrict__ hist,
                                                 int* __restrict__ pbase,
                                                 int* __restrict__ ptot,
                                                 int* __restrict__ ttot) {
    __shared__ int shp[256];
    __shared__ int shv[256];
    int b = blockIdx.x, t = threadIdx.x;
    int v = hist[b * NCHUNK + t];
    int pv = (v + 15) & ~15;
    shp[t] = pv; shv[t] = v;
    __syncthreads();
    for (int d = 1; d < 256; d <<= 1) {
        int a1 = (t >= d) ? shp[t - d] : 0;
        int a2 = (t >= d) ? shv[t - d] : 0;
        __syncthreads();
        shp[t] += a1; shv[t] += a2;
        __syncthreads();
    }
    pbase[b * NCHUNK + t] = shp[t] - pv;   // exclusive padded base
    if (t == 255) { ptot[b] = shp[255]; ttot[b] = shv[255]; }
}

// ---------------- A2b: scan of 196 true bin totals -> bbase ----------------
__global__ __launch_bounds__(256) void k_scanA2b(const int* __restrict__ ttot,
                                                 int* __restrict__ bbase,
                                                 int* __restrict__ off) {
    __shared__ int sh[256];
    int t = threadIdx.x;
    int v = (t < NBIN2) ? ttot[t] : 0;
    sh[t] = v;
    __syncthreads();
    for (int d = 1; d < 256; d <<= 1) {
        int add = (t >= d) ? sh[t - d] : 0;
        __syncthreads();
        sh[t] += add;
        __syncthreads();
    }
    if (t < NBIN2) bbase[t] = sh[t] - v;
    if (t == 0) off[NN] = NE;
}

// ---------------- A3: deterministic placement (no global atomics) ----------------
__global__ __launch_bounds__(256) void k_placeA3(const int* __restrict__ src,
                                                 const int* __restrict__ dst,
                                                 const int* __restrict__ pbase,
                                                 unsigned int* __restrict__ pairs) {
    __shared__ int sbase[NBIN2];
    __shared__ int lcur[NBIN2];
    int k = blockIdx.x, t = threadIdx.x;
    if (t < NBIN2) { sbase[t] = pbase[t * NCHUNK + k]; lcur[t] = 0; }
    __syncthreads();
    int base = k * EPB;
    for (int i = t; i < EPB; i += 256) {
        int e = base + i;
        if (e < NE) {
            int s = src[e], d = dst[e];
            int b = d >> 9;
            int pos = atomicAdd(&lcur[b], 1);
            pairs[(long long)b * CAPBIN + sbase[b] + pos] =
                ((unsigned int)s << 9) | (unsigned int)(d & 511);
        }
    }
    __syncthreads();
    for (int b = t; b < NBIN2; b += 256) {
        int cnt = lcur[b];
        int end = sbase[b] + cnt;
        int pend = sbase[b] + ((cnt + 15) & ~15);
        for (int i = end; i < pend; ++i)
            pairs[(long long)b * CAPBIN + i] = SENT;
    }
}

// ---------------- B: per-bin count -> offsets -> LDS scatter -> sequential dump ----------------
__global__ __launch_bounds__(512) void k_binPlace(const unsigned int* __restrict__ pairs,
                                                  const int* __restrict__ ptot,
                                                  const int* __restrict__ bbase,
                                                  int* __restrict__ off,
                                                  int* __restrict__ ssrc) {
    __shared__ int sbuf[9472];
    __shared__ int lcnt[512];
    __shared__ int sstart[512];
    __shared__ int lcur[512];
    __shared__ int sscan[512];
    int b = blockIdx.x, t = threadIdx.x;
    lcnt[t] = 0; lcur[t] = 0;
    __syncthreads();
    int n = ptot[b];
    const unsigned int* pp = pairs + (long long)b * CAPBIN;
    for (int i = t; i < n; i += 512) {
        unsigned int p = pp[i];
        if (p != SENT) atomicAdd(&lcnt[p & 511], 1);
    }
    __syncthreads();
    int vv = lcnt[t];
    sscan[t] = vv;
    __syncthreads();
    for (int d = 1; d < 512; d <<= 1) {
        int add = (t >= d) ? sscan[t - d] : 0;
        __syncthreads();
        sscan[t] += add;
        __syncthreads();
    }
    sstart[t] = sscan[t] - vv;
    int node = b * 512 + t;
    if (node < NN) off[node] = bbase[b] + sstart[t];
    __syncthreads();
    for (int i = t; i < n; i += 512) {
        unsigned int p = pp[i];
        if (p != SENT) {
            int dl = p & 511;
            int lp = atomicAdd(&lcur[dl], 1);
            sbuf[sstart[dl] + lp] = (int)(p >> 9);
        }
    }
    __syncthreads();
    int len = sscan[511];
    int base = bbase[b];
    for (int i = t; i < len; i += 512)
        ssrc[base + i] = sbuf[i];
}

// ---------------- weight prep: bf16, N-major (B^T) concatenated ----------------
__global__ __launch_bounds__(256) void k_prep_w(
    const float* __restrict__ W1l, const float* __restrict__ W1r,
    const float* __restrict__ W2l, const float* __restrict__ W2r,
    unsigned short* __restrict__ Wcat1t, unsigned short* __restrict__ Wcat2t) {
    for (int i = threadIdx.x; i < 128 * 128; i += 256) {
        int n = i >> 7, k = i & 127;
        float v1 = (k < 64) ? W1l[k * 128 + n] : W1r[(k - 64) * 128 + n];
        Wcat1t[i] = f2bf(v1);
        float v2 = (n < 64) ? W2l[k * 64 + n] : W2r[k * 64 + (n - 64)];
        Wcat2t[i] = f2bf(v2);
    }
}

// ---------------- convert x -> bf16 into Axcat[:,64:128] ----------------
__global__ __launch_bounds__(256) void k_cvt_x(const float* __restrict__ x,
                                               unsigned short* __restrict__ Axcat) {
    int idx = blockIdx.x * blockDim.x + threadIdx.x;  // node*32 + f2
    if (idx >= NN * 32) return;
    int node = idx >> 5, f2 = idx & 31;
    float2 v = *(const float2*)(x + (long long)node * 64 + 2 * f2);
    unsigned int p = (unsigned int)f2bf(v.x) | ((unsigned int)f2bf(v.y) << 16);
    *(unsigned int*)(Axcat + (long long)node * 128 + 64 + 2 * f2) = p;
}

// ---------------- gather-mean (MLP-optimized): idx via coalesced load + shfl ----------------
// half-wave (32 lanes) per node; lane covers 2 feats (uint); 4 feature-loads in flight.
__global__ __launch_bounds__(256) void k_gather_x(const int* __restrict__ ssrc,
                                                  const int* __restrict__ off,
                                                  unsigned short* __restrict__ Axcat) {
    int wv = (blockIdx.x * blockDim.x + threadIdx.x) >> 6;
    int half = (threadIdx.x >> 5) & 1;
    int lane = threadIdx.x & 31;
    int node = wv * 2 + half;
    if (node >= NN) return;
    int o0 = off[node], o1 = off[node + 1];
    float a0 = 0.f, a1 = 0.f;
    for (int base = o0; base < o1; base += 32) {
        int nk = min(32, o1 - base);
        int sidx = (base + lane < o1) ? ssrc[base + lane] : 0;  // coalesced, 32 edges at once
        int k = 0;
        for (; k + 3 < nk; k += 4) {
            int s0 = __shfl(sidx, k, 32);
            int s1 = __shfl(sidx, k + 1, 32);
            int s2 = __shfl(sidx, k + 2, 32);
            int s3 = __shfl(sidx, k + 3, 32);
            unsigned int v0 = *(const unsigned int*)(Axcat + (long long)s0 * 128 + 64 + 2 * lane);
            unsigned int v1 = *(const unsigned int*)(Axcat + (long long)s1 * 128 + 64 + 2 * lane);
            unsigned int v2 = *(const unsigned int*)(Axcat + (long long)s2 * 128 + 64 + 2 * lane);
            unsigned int v3 = *(const unsigned int*)(Axcat + (long long)s3 * 128 + 64 + 2 * lane);
            a0 += bf2f((unsigned short)v0) + bf2f((unsigned short)v1)
                + bf2f((unsigned short)v2) + bf2f((unsigned short)v3);
            a1 += bf2f((unsigned short)(v0 >> 16)) + bf2f((unsigned short)(v1 >> 16))
                + bf2f((unsigned short)(v2 >> 16)) + bf2f((unsigned short)(v3 >> 16));
        }
        for (; k < nk; ++k) {
            int s0 = __shfl(sidx, k, 32);
            unsigned int v0 = *(const unsigned int*)(Axcat + (long long)s0 * 128 + 64 + 2 * lane);
            a0 += bf2f((unsigned short)v0);
            a1 += bf2f((unsigned short)(v0 >> 16));
        }
    }
    int deg = o1 - o0;
    float inv = (deg > 0) ? 1.f / (float)deg : 0.f;
    unsigned int p = (unsigned int)f2bf(a0 * inv) | ((unsigned int)f2bf(a1 * inv) << 16);
    *(unsigned int*)(Axcat + (long long)node * 128 + 2 * lane) = p;
}

// ---------------- gather-mean of bf16 y1 + z + relu -> out (same MLP structure) ----------------
__global__ __launch_bounds__(256) void k_gather_out(const int* __restrict__ ssrc,
                                                    const int* __restrict__ off,
                                                    const unsigned short* __restrict__ y1b,
                                                    const float* __restrict__ zbuf,
                                                    float* __restrict__ out) {
    int wv = (blockIdx.x * blockDim.x + threadIdx.x) >> 6;
    int half = (threadIdx.x >> 5) & 1;
    int lane = threadIdx.x & 31;
    int node = wv * 2 + half;
    if (node >= NN) return;
    int o0 = off[node], o1 = off[node + 1];
    float a0 = 0.f, a1 = 0.f;
    for (int base = o0; base < o1; base += 32) {
        int nk = min(32, o1 - base);
        int sidx = (base + lane < o1) ? ssrc[base + lane] : 0;
        int k = 0;
        for (; k + 3 < nk; k += 4) {
            int s0 = __shfl(sidx, k, 32);
            int s1 = __shfl(sidx, k + 1, 32);
            int s2 = __shfl(sidx, k + 2, 32);
            int s3 = __shfl(sidx, k + 3, 32);
            unsigned int v0 = *(const unsigned int*)(y1b + (long long)s0 * 64 + 2 * lane);
            unsigned int v1 = *(const unsigned int*)(y1b + (long long)s1 * 64 + 2 * lane);
            unsigned int v2 = *(const unsigned int*)(y1b + (long long)s2 * 64 + 2 * lane);
            unsigned int v3 = *(const unsigned int*)(y1b + (long long)s3 * 64 + 2 * lane);
            a0 += bf2f((unsigned short)v0) + bf2f((unsigned short)v1)
                + bf2f((unsigned short)v2) + bf2f((unsigned short)v3);
            a1 += bf2f((unsigned short)(v0 >> 16)) + bf2f((unsigned short)(v1 >> 16))
                + bf2f((unsigned short)(v2 >> 16)) + bf2f((unsigned short)(v3 >> 16));
        }
        for (; k < nk; ++k) {
            int s0 = __shfl(sidx, k, 32);
            unsigned int v0 = *(const unsigned int*)(y1b + (long long)s0 * 64 + 2 * lane);
            a0 += bf2f((unsigned short)v0);
            a1 += bf2f((unsigned short)(v0 >> 16));
        }
    }
    int deg = o1 - o0;
    float inv = (deg > 0) ? 1.f / (float)deg : 0.f;
    float2 zz = *(const float2*)(zbuf + (long long)node * 64 + 2 * lane);
    float2 o;
    o.x = fmaxf(a0 * inv + zz.x, 0.f);
    o.y = fmaxf(a1 * inv + zz.y, 0.f);
    *(float2*)(out + (long long)node * 64 + 2 * lane) = o;
}

// ---------------- MFMA GEMM: A[NROWS][128]bf16 @ Bt[128][128]bf16 ----------------
template<int MODE>
__global__ __launch_bounds__(256) void k_gemm(
    const unsigned short* __restrict__ A,
    const unsigned short* __restrict__ Bt,
    const float* __restrict__ bias,
    unsigned short* __restrict__ outb,
    float* __restrict__ outf) {
    __shared__ unsigned short lds[2 * 128 * 128];  // A tile then B, 64 KB
    __shared__ float sBias[128];
    const int tid = threadIdx.x;
    const int wid = tid >> 6;
    const int lane = tid & 63;

    // MODE 1 epilogue reads sBias[col] with col in [64,128) -> store b2 there.
    if (tid < 128) sBias[tid] = (MODE == 0) ? bias[tid] : ((tid >= 64) ? bias[tid - 64] : 0.f);

    const char* Ag = (const char*)(A + (long long)blockIdx.x * 128 * 128);
    const char* Bg = (const char*)Bt;
    char* ldsc = (char*)lds;
    #pragma unroll
    for (int j = 0; j < 8; ++j) {
        int g = wid * 512 + j * 64 + lane;        // granule (16B) index in [0,2048)
        int gs = g ^ ((g >> 4) & 7);              // pre-swizzled source granule
        GLOAD_LDS16(Ag + (long long)gs * 16, ldsc + (wid * 8192 + j * 1024));
        GLOAD_LDS16(Bg + (long long)gs * 16, ldsc + 32768 + (wid * 8192 + j * 1024));
    }
    __syncthreads();

    const int rA = lane & 15;
    const int kq = lane >> 4;                     // 0..3
    f32x4 acc[2][8] = {};

    #pragma unroll
    for (int ks = 0; ks < 4; ++ks) {
        const int kbyte = ks * 64 + kq * 16;
        bf16x8 a[2], b[8];
        #pragma unroll
        for (int m = 0; m < 2; ++m) {
            int row = wid * 32 + m * 16 + rA;
            int byte = row * 256 + (kbyte ^ ((row & 7) << 4));
            a[m] = *(const bf16x8*)(ldsc + byte);
        }
        #pragma unroll
        for (int n = 0; n < 8; ++n) {
            int row = n * 16 + rA;
            int byte = 32768 + row * 256 + (kbyte ^ ((row & 7) << 4));
            b[n] = *(const bf16x8*)(ldsc + byte);
        }
        #pragma unroll
        for (int m = 0; m < 2; ++m)
            #pragma unroll
            for (int n = 0; n < 8; ++n)
                acc[m][n] = __builtin_amdgcn_mfma_f32_16x16x32_bf16(a[m], b[n], acc[m][n], 0, 0, 0);
    }

    #pragma unroll
    for (int m = 0; m < 2; ++m) {
        #pragma unroll
        for (int n = 0; n < 8; ++n) {
            int col = n * 16 + rA;
            long long row0 = (long long)blockIdx.x * 128 + wid * 32 + m * 16 + kq * 4;
            #pragma unroll
            for (int r = 0; r < 4; ++r) {
                long long row = row0 + r;
                if (row < NN) {
                    float v = acc[m][n][r];
                    if (MODE == 0) {
                        v = fmaxf(v + sBias[col], 0.f);
                        outb[row * 128 + col] = f2bf(v);
                    } else {
                        if (col < 64) outb[row * 64 + col] = f2bf(v);
                        else          outf[row * 64 + (col - 64)] = v + sBias[col];
                    }
                }
            }
        }
    }
}

extern "C" void kernel_launch(void* const* d_in, const int* in_sizes, int n_in,
                              void* d_out, int out_size, void* d_ws, size_t ws_size,
                              hipStream_t stream) {
    const float* x   = (const float*)d_in[0];
    const int*   ei  = (const int*)d_in[1];
    const int*   src = ei;
    const int*   dst = ei + NE;
    const float* W1l = (const float*)d_in[2];
    const float* b1  = (const float*)d_in[3];
    const float* W1r = (const float*)d_in[4];
    const float* W2l = (const float*)d_in[5];
    const float* b2  = (const float*)d_in[6];
    const float* W2r = (const float*)d_in[7];
    float* out = (float*)d_out;

    // workspace layout (bytes), all buffers fully written before read (no memset):
    //   [0,         400640)     off    int[NN+1]
    //   [400640,    6800640)    ssrc   int[NE]
    //   [6800640,   7001344)    hist   int[NBIN2*NCHUNK]
    //   [7001344,   7202048)    pbase  int[NBIN2*NCHUNK]
    //   [7202048,   7203072)    ptot   int[256]
    //   [7203072,   7204096)    ttot   int[256]
    //   [7204096,   7205120)    bbase  int[256]
    //   [7205120,   17641728)   pairs  uint[NBIN2*CAPBIN]
    //   [17641728,  43266304)   Axcat  bf16[NROWS][128]
    //   [43266304,  68890880)   h1b    bf16[NROWS][128]
    //   [68890880,  81690880)   y1b    bf16[NN][64]
    //   [81690880,  107290880)  zbuf   f32 [NN][64]
    //   [107290880, 107323648)  Wc1    bf16[128][128]
    //   [107323648, 107356416)  Wc2    bf16[128][128]
    char* ws = (char*)d_ws;
    int*   off   = (int*)ws;
    int*   ssrc  = (int*)(ws + 400640);
    int*   hist  = (int*)(ws + 6800640);
    int*   pbase = (int*)(ws + 7001344);
    int*   ptot  = (int*)(ws + 7202048);
    int*   ttot  = (int*)(ws + 7203072);
    int*   bbase = (int*)(ws + 7204096);
    unsigned int* pairs = (unsigned int*)(ws + 7205120);
    unsigned short* Axcat = (unsigned short*)(ws + 17641728);
    unsigned short* h1b   = (unsigned short*)(ws + 43266304);
    unsigned short* y1b   = (unsigned short*)(ws + 68890880);
    float*          zbuf  = (float*)(ws + 81690880);
    unsigned short* Wc1   = (unsigned short*)(ws + 107290880);
    unsigned short* Wc2   = (unsigned short*)(ws + 107323648);

    k_hist<<<NCHUNK, 256, 0, stream>>>(dst, hist);
    k_scanA2a<<<NBIN2, 256, 0, stream>>>(hist, pbase, ptot, ttot);
    k_scanA2b<<<1, 256, 0, stream>>>(ttot, bbase, off);
    k_placeA3<<<NCHUNK, 256, 0, stream>>>(src, dst, pbase, pairs);
    k_binPlace<<<NBIN2, 512, 0, stream>>>(pairs, ptot, bbase, off, ssrc);
    k_prep_w<<<1, 256, 0, stream>>>(W1l, W1r, W2l, W2r, Wc1, Wc2);
    k_cvt_x<<<(NN * 32 + 255) / 256, 256, 0, stream>>>(x, Axcat);
    k_gather_x<<<(NN / 2 * 64 + 255) / 256, 256, 0, stream>>>(ssrc, off, Axcat);
    k_gemm<0><<<NROWS / 128, 256, 0, stream>>>(Axcat, Wc1, b1, h1b, nullptr);
    k_gemm<1><<<NROWS / 128, 256, 0, stream>>>(h1b, Wc2, b2, y1b, zbuf);
    k_gather_out<<<(NN / 2 * 64 + 255) / 256, 256, 0, stream>>>(ssrc, off, y1b, zbuf, out);
}

// Round 11
// 244.644 us; speedup vs baseline: 6.7446x; 1.0534x over previous
//
#include <hip/hip_runtime.h>
#include <hip/hip_bf16.h>

#define NN 100000
#define NE 1600000
#define NROWS 100096   // 782 * 128, padded row count for GEMM tiles
#define NBIN2 196      // ceil(NN/512) bins of 512 nodes (dst>>9)
#define NCHUNK 256     // edge chunks (= placement blocks)
#define EPB 6250       // edges per chunk (256*6250 = NE exactly)
#define CAPBIN 13312   // padded per-bin capacity (mean 8163 + pad <=3840 + slack)
#define SENT 0xFFFFFFFFu

typedef short bf16x8 __attribute__((ext_vector_type(8)));
typedef float f32x4 __attribute__((ext_vector_type(4)));

static __device__ __forceinline__ unsigned short f2bf(float f) {
    __hip_bfloat16 h = __float2bfloat16(f);
    return *reinterpret_cast<unsigned short*>(&h);
}
static __device__ __forceinline__ float bf2f(unsigned short u) {
    union { unsigned int i; float f; } v;
    v.i = ((unsigned int)u) << 16;
    return v.f;
}

#define GLOAD_LDS16(g, l) \
    __builtin_amdgcn_global_load_lds((const __attribute__((address_space(1))) void*)(g), \
                                     (__attribute__((address_space(3))) void*)(l), 16, 0, 0)

// ---------------- A1: per-chunk histogram over 196 bins ----------------
__global__ __launch_bounds__(256) void k_hist(const int* __restrict__ dst,
                                              int* __restrict__ hist) {
    __shared__ int lcnt[NBIN2];
    int k = blockIdx.x, t = threadIdx.x;
    if (t < NBIN2) lcnt[t] = 0;
    __syncthreads();
    int base = k * EPB;
    for (int i = t; i < EPB; i += 256) {
        int e = base + i;
        if (e < NE) atomicAdd(&lcnt[dst[e] >> 9], 1);
    }
    __syncthreads();
    if (t < NBIN2) hist[t * NCHUNK + k] = lcnt[t];   // [bin][chunk]
}

// ---------------- A2a: per-bin scan over chunks (padded to 16) ----------------
__global__ __launch_bounds__(256) void k_scanA2a(const int* __restrict__ hist,
                                                 int* __restrict__ pbase,
                                                 int* __restrict__ ptot,
                                                 int* __restrict__ ttot) {
    __shared__ int shp[256];
    __shared__ int shv[256];
    int b = blockIdx.x, t = threadIdx.x;
    int v = hist[b * NCHUNK + t];
    int pv = (v + 15) & ~15;
    shp[t] = pv; shv[t] = v;
    __syncthreads();
    for (int d = 1; d < 256; d <<= 1) {
        int a1 = (t >= d) ? shp[t - d] : 0;
        int a2 = (t >= d) ? shv[t - d] : 0;
        __syncthreads();
        shp[t] += a1; shv[t] += a2;
        __syncthreads();
    }
    pbase[b * NCHUNK + t] = shp[t] - pv;   // exclusive padded base
    if (t == 255) { ptot[b] = shp[255]; ttot[b] = shv[255]; }
}

// ---------------- A2b: scan of 196 true bin totals -> bbase ----------------
__global__ __launch_bounds__(256) void k_scanA2b(const int* __restrict__ ttot,
                                                 int* __restrict__ bbase,
                                                 int* __restrict__ off) {
    __shared__ int sh[256];
    int t = threadIdx.x;
    int v = (t < NBIN2) ? ttot[t] : 0;
    sh[t] = v;
    __syncthreads();
    for (int d = 1; d < 256; d <<= 1) {
        int add = (t >= d) ? sh[t - d] : 0;
        __syncthreads();
        sh[t] += add;
        __syncthreads();
    }
    if (t < NBIN2) bbase[t] = sh[t] - v;
    if (t == 0) off[NN] = NE;
}

// ---------------- A3: deterministic placement (no global atomics) ----------------
__global__ __launch_bounds__(256) void k_placeA3(const int* __restrict__ src,
                                                 const int* __restrict__ dst,
                                                 const int* __restrict__ pbase,
                                                 unsigned int* __restrict__ pairs) {
    __shared__ int sbase[NBIN2];
    __shared__ int lcur[NBIN2];
    int k = blockIdx.x, t = threadIdx.x;
    if (t < NBIN2) { sbase[t] = pbase[t * NCHUNK + k]; lcur[t] = 0; }
    __syncthreads();
    int base = k * EPB;
    for (int i = t; i < EPB; i += 256) {
        int e = base + i;
        if (e < NE) {
            int s = src[e], d = dst[e];
            int b = d >> 9;
            int pos = atomicAdd(&lcur[b], 1);
            pairs[(long long)b * CAPBIN + sbase[b] + pos] =
                ((unsigned int)s << 9) | (unsigned int)(d & 511);
        }
    }
    __syncthreads();
    for (int b = t; b < NBIN2; b += 256) {
        int cnt = lcur[b];
        int end = sbase[b] + cnt;
        int pend = sbase[b] + ((cnt + 15) & ~15);
        for (int i = end; i < pend; ++i)
            pairs[(long long)b * CAPBIN + i] = SENT;
    }
}

// ---------------- B: per-bin count -> offsets -> LDS scatter -> sequential dump ----------------
__global__ __launch_bounds__(512) void k_binPlace(const unsigned int* __restrict__ pairs,
                                                  const int* __restrict__ ptot,
                                                  const int* __restrict__ bbase,
                                                  int* __restrict__ off,
                                                  int* __restrict__ ssrc) {
    __shared__ int sbuf[9472];
    __shared__ int lcnt[512];
    __shared__ int sstart[512];
    __shared__ int lcur[512];
    __shared__ int sscan[512];
    int b = blockIdx.x, t = threadIdx.x;
    lcnt[t] = 0; lcur[t] = 0;
    __syncthreads();
    int n = ptot[b];
    const unsigned int* pp = pairs + (long long)b * CAPBIN;
    for (int i = t; i < n; i += 512) {
        unsigned int p = pp[i];
        if (p != SENT) atomicAdd(&lcnt[p & 511], 1);
    }
    __syncthreads();
    int vv = lcnt[t];
    sscan[t] = vv;
    __syncthreads();
    for (int d = 1; d < 512; d <<= 1) {
        int add = (t >= d) ? sscan[t - d] : 0;
        __syncthreads();
        sscan[t] += add;
        __syncthreads();
    }
    sstart[t] = sscan[t] - vv;
    int node = b * 512 + t;
    if (node < NN) off[node] = bbase[b] + sstart[t];
    __syncthreads();
    for (int i = t; i < n; i += 512) {
        unsigned int p = pp[i];
        if (p != SENT) {
            int dl = p & 511;
            int lp = atomicAdd(&lcur[dl], 1);
            sbuf[sstart[dl] + lp] = (int)(p >> 9);
        }
    }
    __syncthreads();
    int len = sscan[511];
    int base = bbase[b];
    for (int i = t; i < len; i += 512)
        ssrc[base + i] = sbuf[i];
}

// ---------------- fused: convert x -> bf16 (blocks 0..12499) + weight prep (block 12500) ----------------
__global__ __launch_bounds__(256) void k_cvt_prep(const float* __restrict__ x,
                                                  unsigned short* __restrict__ Axcat,
                                                  const float* __restrict__ W1l,
                                                  const float* __restrict__ W1r,
                                                  const float* __restrict__ W2l,
                                                  const float* __restrict__ W2r,
                                                  unsigned short* __restrict__ Wcat1t,
                                                  unsigned short* __restrict__ Wcat2t) {
    if (blockIdx.x == 12500) {
        // Wcat1t[n][k] = k<64 ? W1l[k][n] : W1r[k-64][n]; Wcat2t[n][k] = n<64 ? W2l[k][n] : W2r[k][n-64]
        for (int i = threadIdx.x; i < 128 * 128; i += 256) {
            int n = i >> 7, k = i & 127;
            float v1 = (k < 64) ? W1l[k * 128 + n] : W1r[(k - 64) * 128 + n];
            Wcat1t[i] = f2bf(v1);
            float v2 = (n < 64) ? W2l[k * 64 + n] : W2r[k * 64 + (n - 64)];
            Wcat2t[i] = f2bf(v2);
        }
        return;
    }
    int idx = blockIdx.x * blockDim.x + threadIdx.x;  // node*32 + f2
    if (idx >= NN * 32) return;
    int node = idx >> 5, f2 = idx & 31;
    float2 v = *(const float2*)(x + (long long)node * 64 + 2 * f2);
    unsigned int p = (unsigned int)f2bf(v.x) | ((unsigned int)f2bf(v.y) << 16);
    *(unsigned int*)(Axcat + (long long)node * 128 + 64 + 2 * f2) = p;
}

// ---------------- gather-mean (8-deep MLP): idx via coalesced load + shfl ----------------
// half-wave (32 lanes) per node; lane covers 2 feats (uint); 8 feature-loads in flight.
__global__ __launch_bounds__(256) void k_gather_x(const int* __restrict__ ssrc,
                                                  const int* __restrict__ off,
                                                  unsigned short* __restrict__ Axcat) {
    int wv = (blockIdx.x * blockDim.x + threadIdx.x) >> 6;
    int half = (threadIdx.x >> 5) & 1;
    int lane = threadIdx.x & 31;
    int node = wv * 2 + half;
    if (node >= NN) return;
    int o0 = off[node], o1 = off[node + 1];
    float a0 = 0.f, a1 = 0.f;
    for (int base = o0; base < o1; base += 32) {
        int nk = min(32, o1 - base);
        int sidx = (base + lane < o1) ? ssrc[base + lane] : 0;  // coalesced, 32 edges at once
        int k = 0;
        for (; k + 7 < nk; k += 8) {
            unsigned int v0 = *(const unsigned int*)(Axcat + (long long)__shfl(sidx, k    , 32) * 128 + 64 + 2 * lane);
            unsigned int v1 = *(const unsigned int*)(Axcat + (long long)__shfl(sidx, k + 1, 32) * 128 + 64 + 2 * lane);
            unsigned int v2 = *(const unsigned int*)(Axcat + (long long)__shfl(sidx, k + 2, 32) * 128 + 64 + 2 * lane);
            unsigned int v3 = *(const unsigned int*)(Axcat + (long long)__shfl(sidx, k + 3, 32) * 128 + 64 + 2 * lane);
            unsigned int v4 = *(const unsigned int*)(Axcat + (long long)__shfl(sidx, k + 4, 32) * 128 + 64 + 2 * lane);
            unsigned int v5 = *(const unsigned int*)(Axcat + (long long)__shfl(sidx, k + 5, 32) * 128 + 64 + 2 * lane);
            unsigned int v6 = *(const unsigned int*)(Axcat + (long long)__shfl(sidx, k + 6, 32) * 128 + 64 + 2 * lane);
            unsigned int v7 = *(const unsigned int*)(Axcat + (long long)__shfl(sidx, k + 7, 32) * 128 + 64 + 2 * lane);
            a0 += bf2f((unsigned short)v0) + bf2f((unsigned short)v1)
                + bf2f((unsigned short)v2) + bf2f((unsigned short)v3)
                + bf2f((unsigned short)v4) + bf2f((unsigned short)v5)
                + bf2f((unsigned short)v6) + bf2f((unsigned short)v7);
            a1 += bf2f((unsigned short)(v0 >> 16)) + bf2f((unsigned short)(v1 >> 16))
                + bf2f((unsigned short)(v2 >> 16)) + bf2f((unsigned short)(v3 >> 16))
                + bf2f((unsigned short)(v4 >> 16)) + bf2f((unsigned short)(v5 >> 16))
                + bf2f((unsigned short)(v6 >> 16)) + bf2f((unsigned short)(v7 >> 16));
        }
        for (; k + 3 < nk; k += 4) {
            unsigned int v0 = *(const unsigned int*)(Axcat + (long long)__shfl(sidx, k    , 32) * 128 + 64 + 2 * lane);
            unsigned int v1 = *(const unsigned int*)(Axcat + (long long)__shfl(sidx, k + 1, 32) * 128 + 64 + 2 * lane);
            unsigned int v2 = *(const unsigned int*)(Axcat + (long long)__shfl(sidx, k + 2, 32) * 128 + 64 + 2 * lane);
            unsigned int v3 = *(const unsigned int*)(Axcat + (long long)__shfl(sidx, k + 3, 32) * 128 + 64 + 2 * lane);
            a0 += bf2f((unsigned short)v0) + bf2f((unsigned short)v1)
                + bf2f((unsigned short)v2) + bf2f((unsigned short)v3);
            a1 += bf2f((unsigned short)(v0 >> 16)) + bf2f((unsigned short)(v1 >> 16))
                + bf2f((unsigned short)(v2 >> 16)) + bf2f((unsigned short)(v3 >> 16));
        }
        for (; k < nk; ++k) {
            unsigned int v0 = *(const unsigned int*)(Axcat + (long long)__shfl(sidx, k, 32) * 128 + 64 + 2 * lane);
            a0 += bf2f((unsigned short)v0);
            a1 += bf2f((unsigned short)(v0 >> 16));
        }
    }
    int deg = o1 - o0;
    float inv = (deg > 0) ? 1.f / (float)deg : 0.f;
    unsigned int p = (unsigned int)f2bf(a0 * inv) | ((unsigned int)f2bf(a1 * inv) << 16);
    *(unsigned int*)(Axcat + (long long)node * 128 + 2 * lane) = p;
}

// ---------------- gather-mean of bf16 y1 + bf16 z + relu -> out (8-deep MLP) ----------------
__global__ __launch_bounds__(256) void k_gather_out(const int* __restrict__ ssrc,
                                                    const int* __restrict__ off,
                                                    const unsigned short* __restrict__ y1b,
                                                    const unsigned short* __restrict__ zb,
                                                    float* __restrict__ out) {
    int wv = (blockIdx.x * blockDim.x + threadIdx.x) >> 6;
    int half = (threadIdx.x >> 5) & 1;
    int lane = threadIdx.x & 31;
    int node = wv * 2 + half;
    if (node >= NN) return;
    int o0 = off[node], o1 = off[node + 1];
    float a0 = 0.f, a1 = 0.f;
    for (int base = o0; base < o1; base += 32) {
        int nk = min(32, o1 - base);
        int sidx = (base + lane < o1) ? ssrc[base + lane] : 0;
        int k = 0;
        for (; k + 7 < nk; k += 8) {
            unsigned int v0 = *(const unsigned int*)(y1b + (long long)__shfl(sidx, k    , 32) * 64 + 2 * lane);
            unsigned int v1 = *(const unsigned int*)(y1b + (long long)__shfl(sidx, k + 1, 32) * 64 + 2 * lane);
            unsigned int v2 = *(const unsigned int*)(y1b + (long long)__shfl(sidx, k + 2, 32) * 64 + 2 * lane);
            unsigned int v3 = *(const unsigned int*)(y1b + (long long)__shfl(sidx, k + 3, 32) * 64 + 2 * lane);
            unsigned int v4 = *(const unsigned int*)(y1b + (long long)__shfl(sidx, k + 4, 32) * 64 + 2 * lane);
            unsigned int v5 = *(const unsigned int*)(y1b + (long long)__shfl(sidx, k + 5, 32) * 64 + 2 * lane);
            unsigned int v6 = *(const unsigned int*)(y1b + (long long)__shfl(sidx, k + 6, 32) * 64 + 2 * lane);
            unsigned int v7 = *(const unsigned int*)(y1b + (long long)__shfl(sidx, k + 7, 32) * 64 + 2 * lane);
            a0 += bf2f((unsigned short)v0) + bf2f((unsigned short)v1)
                + bf2f((unsigned short)v2) + bf2f((unsigned short)v3)
                + bf2f((unsigned short)v4) + bf2f((unsigned short)v5)
                + bf2f((unsigned short)v6) + bf2f((unsigned short)v7);
            a1 += bf2f((unsigned short)(v0 >> 16)) + bf2f((unsigned short)(v1 >> 16))
                + bf2f((unsigned short)(v2 >> 16)) + bf2f((unsigned short)(v3 >> 16))
                + bf2f((unsigned short)(v4 >> 16)) + bf2f((unsigned short)(v5 >> 16))
                + bf2f((unsigned short)(v6 >> 16)) + bf2f((unsigned short)(v7 >> 16));
        }
        for (; k + 3 < nk; k += 4) {
            unsigned int v0 = *(const unsigned int*)(y1b + (long long)__shfl(sidx, k    , 32) * 64 + 2 * lane);
            unsigned int v1 = *(const unsigned int*)(y1b + (long long)__shfl(sidx, k + 1, 32) * 64 + 2 * lane);
            unsigned int v2 = *(const unsigned int*)(y1b + (long long)__shfl(sidx, k + 2, 32) * 64 + 2 * lane);
            unsigned int v3 = *(const unsigned int*)(y1b + (long long)__shfl(sidx, k + 3, 32) * 64 + 2 * lane);
            a0 += bf2f((unsigned short)v0) + bf2f((unsigned short)v1)
                + bf2f((unsigned short)v2) + bf2f((unsigned short)v3);
            a1 += bf2f((unsigned short)(v0 >> 16)) + bf2f((unsigned short)(v1 >> 16))
                + bf2f((unsigned short)(v2 >> 16)) + bf2f((unsigned short)(v3 >> 16));
        }
        for (; k < nk; ++k) {
            unsigned int v0 = *(const unsigned int*)(y1b + (long long)__shfl(sidx, k, 32) * 64 + 2 * lane);
            a0 += bf2f((unsigned short)v0);
            a1 += bf2f((unsigned short)(v0 >> 16));
        }
    }
    int deg = o1 - o0;
    float inv = (deg > 0) ? 1.f / (float)deg : 0.f;
    unsigned int zz = *(const unsigned int*)(zb + (long long)node * 64 + 2 * lane);
    float2 o;
    o.x = fmaxf(a0 * inv + bf2f((unsigned short)zz), 0.f);
    o.y = fmaxf(a1 * inv + bf2f((unsigned short)(zz >> 16)), 0.f);
    *(float2*)(out + (long long)node * 64 + 2 * lane) = o;
}

// ---------------- MFMA GEMM: A[NROWS][128]bf16 @ Bt[128][128]bf16 ----------------
// MODE 0: outb = relu(A@B + bias[128]) bf16 [NROWS][128]  (h1)
// MODE 1: cols 0:64 -> outb bf16 (y1); cols 64:128 -> outz bf16 = acc + b2[col-64] (z)
template<int MODE>
__global__ __launch_bounds__(256) void k_gemm(
    const unsigned short* __restrict__ A,
    const unsigned short* __restrict__ Bt,
    const float* __restrict__ bias,
    unsigned short* __restrict__ outb,
    unsigned short* __restrict__ outz) {
    __shared__ unsigned short lds[2 * 128 * 128];  // A tile then B, 64 KB
    __shared__ float sBias[128];
    const int tid = threadIdx.x;
    const int wid = tid >> 6;
    const int lane = tid & 63;

    // MODE 1 epilogue reads sBias[col] with col in [64,128) -> store b2 there.
    if (tid < 128) sBias[tid] = (MODE == 0) ? bias[tid] : ((tid >= 64) ? bias[tid - 64] : 0.f);

    const char* Ag = (const char*)(A + (long long)blockIdx.x * 128 * 128);
    const char* Bg = (const char*)Bt;
    char* ldsc = (char*)lds;
    #pragma unroll
    for (int j = 0; j < 8; ++j) {
        int g = wid * 512 + j * 64 + lane;        // granule (16B) index in [0,2048)
        int gs = g ^ ((g >> 4) & 7);              // pre-swizzled source granule
        GLOAD_LDS16(Ag + (long long)gs * 16, ldsc + (wid * 8192 + j * 1024));
        GLOAD_LDS16(Bg + (long long)gs * 16, ldsc + 32768 + (wid * 8192 + j * 1024));
    }
    __syncthreads();

    const int rA = lane & 15;
    const int kq = lane >> 4;                     // 0..3
    f32x4 acc[2][8] = {};

    #pragma unroll
    for (int ks = 0; ks < 4; ++ks) {
        const int kbyte = ks * 64 + kq * 16;
        bf16x8 a[2], b[8];
        #pragma unroll
        for (int m = 0; m < 2; ++m) {
            int row = wid * 32 + m * 16 + rA;
            int byte = row * 256 + (kbyte ^ ((row & 7) << 4));
            a[m] = *(const bf16x8*)(ldsc + byte);
        }
        #pragma unroll
        for (int n = 0; n < 8; ++n) {
            int row = n * 16 + rA;
            int byte = 32768 + row * 256 + (kbyte ^ ((row & 7) << 4));
            b[n] = *(const bf16x8*)(ldsc + byte);
        }
        #pragma unroll
        for (int m = 0; m < 2; ++m)
            #pragma unroll
            for (int n = 0; n < 8; ++n)
                acc[m][n] = __builtin_amdgcn_mfma_f32_16x16x32_bf16(a[m], b[n], acc[m][n], 0, 0, 0);
    }

    #pragma unroll
    for (int m = 0; m < 2; ++m) {
        #pragma unroll
        for (int n = 0; n < 8; ++n) {
            int col = n * 16 + rA;
            long long row0 = (long long)blockIdx.x * 128 + wid * 32 + m * 16 + kq * 4;
            #pragma unroll
            for (int r = 0; r < 4; ++r) {
                long long row = row0 + r;
                if (row < NN) {
                    float v = acc[m][n][r];
                    if (MODE == 0) {
                        v = fmaxf(v + sBias[col], 0.f);
                        outb[row * 128 + col] = f2bf(v);
                    } else {
                        if (col < 64) outb[row * 64 + col] = f2bf(v);
                        else          outz[row * 64 + (col - 64)] = f2bf(v + sBias[col]);
                    }
                }
            }
        }
    }
}

extern "C" void kernel_launch(void* const* d_in, const int* in_sizes, int n_in,
                              void* d_out, int out_size, void* d_ws, size_t ws_size,
                              hipStream_t stream) {
    const float* x   = (const float*)d_in[0];
    const int*   ei  = (const int*)d_in[1];
    const int*   src = ei;
    const int*   dst = ei + NE;
    const float* W1l = (const float*)d_in[2];
    const float* b1  = (const float*)d_in[3];
    const float* W1r = (const float*)d_in[4];
    const float* W2l = (const float*)d_in[5];
    const float* b2  = (const float*)d_in[6];
    const float* W2r = (const float*)d_in[7];
    float* out = (float*)d_out;

    // workspace layout (bytes), all buffers fully written before read (no memset):
    //   [0,         400640)     off    int[NN+1]
    //   [400640,    6800640)    ssrc   int[NE]
    //   [6800640,   7001344)    hist   int[NBIN2*NCHUNK]
    //   [7001344,   7202048)    pbase  int[NBIN2*NCHUNK]
    //   [7202048,   7203072)    ptot   int[256]
    //   [7203072,   7204096)    ttot   int[256]
    //   [7204096,   7205120)    bbase  int[256]
    //   [7205120,   17641728)   pairs  uint[NBIN2*CAPBIN]
    //   [17641728,  43266304)   Axcat  bf16[NROWS][128]
    //   [43266304,  68890880)   h1b    bf16[NROWS][128]
    //   [68890880,  81690880)   y1b    bf16[NN][64]
    //   [81690880,  94490880)   zb     bf16[NN][64]
    //   [94490880,  94523648)   Wc1    bf16[128][128]
    //   [94523648,  94556416)   Wc2    bf16[128][128]
    char* ws = (char*)d_ws;
    int*   off   = (int*)ws;
    int*   ssrc  = (int*)(ws + 400640);
    int*   hist  = (int*)(ws + 6800640);
    int*   pbase = (int*)(ws + 7001344);
    int*   ptot  = (int*)(ws + 7202048);
    int*   ttot  = (int*)(ws + 7203072);
    int*   bbase = (int*)(ws + 7204096);
    unsigned int* pairs = (unsigned int*)(ws + 7205120);
    unsigned short* Axcat = (unsigned short*)(ws + 17641728);
    unsigned short* h1b   = (unsigned short*)(ws + 43266304);
    unsigned short* y1b   = (unsigned short*)(ws + 68890880);
    unsigned short* zb    = (unsigned short*)(ws + 81690880);
    unsigned short* Wc1   = (unsigned short*)(ws + 94490880);
    unsigned short* Wc2   = (unsigned short*)(ws + 94523648);

    k_hist<<<NCHUNK, 256, 0, stream>>>(dst, hist);
    k_scanA2a<<<NBIN2, 256, 0, stream>>>(hist, pbase, ptot, ttot);
    k_scanA2b<<<1, 256, 0, stream>>>(ttot, bbase, off);
    k_placeA3<<<NCHUNK, 256, 0, stream>>>(src, dst, pbase, pairs);
    k_binPlace<<<NBIN2, 512, 0, stream>>>(pairs, ptot, bbase, off, ssrc);
    k_cvt_prep<<<12501, 256, 0, stream>>>(x, Axcat, W1l, W1r, W2l, W2r, Wc1, Wc2);
    k_gather_x<<<(NN / 2 * 64 + 255) / 256, 256, 0, stream>>>(ssrc, off, Axcat);
    k_gemm<0><<<NROWS / 128, 256, 0, stream>>>(Axcat, Wc1, b1, h1b, nullptr);
    k_gemm<1><<<NROWS / 128, 256, 0, stream>>>(h1b, Wc2, b2, y1b, zb);
    k_gather_out<<<(NN / 2 * 64 + 255) / 256, 256, 0, stream>>>(ssrc, off, y1b, zb, out);
}